// Round 6
// baseline (427.342 us; speedup 1.0000x reference)
//
#include <hip/hip_runtime.h>
#include <math.h>

#define S 1024
#define DM 512
#define H 8
#define HD 64
#define NH 8          // n_hashes
#define NB 16         // n_buckets
#define N 8192        // B*H*S
#define SCALE 0.125f  // 1/sqrt(64)

typedef __attribute__((ext_vector_type(4))) float f32x4;
typedef __attribute__((ext_vector_type(8))) short s16x8;
typedef __attribute__((ext_vector_type(4))) short s16x4;

__device__ __forceinline__ short f2bf(float f) {  // RTNE float->bf16
  union { float f; unsigned u; } a; a.f = f;
  unsigned r = a.u + 0x7fffu + ((a.u >> 16) & 1u);
  return (short)(r >> 16);
}
__device__ __forceinline__ int f2bf2(float lo, float hi) {
  return (int)(unsigned short)f2bf(lo) | (((int)f2bf(hi)) << 16);
}

#if __has_builtin(__builtin_amdgcn_mfma_f32_16x16x16_bf16)
#define MFMA_PV(a, b, c) __builtin_amdgcn_mfma_f32_16x16x16_bf16(a, b, c, 0, 0, 0)
#else
#define MFMA_PV(a, b, c) __builtin_amdgcn_mfma_f32_16x16x16bf16_1k(a, b, c, 0, 0, 0)
#endif

// ---------------- K1: fused dual projection GEMM (qk and v), 32x64 tiles
// grid 512 = 32 sb x 8 db x 2 mat  (2 blocks/CU)
#define GBS 32
#define GBK 32
__global__ __launch_bounds__(256) void proj2_kernel(
    const float* __restrict__ x,
    const float* __restrict__ wqk, const float* __restrict__ bqk,
    const float* __restrict__ wv,  const float* __restrict__ bv,
    float* __restrict__ qkf, float* __restrict__ vf) {
  int sb  = blockIdx.x & 31;
  int db  = (blockIdx.x >> 5) & 7;
  int mat = blockIdx.x >> 8;  // 0=qk, 1=v
  const float* w    = mat ? wv : wqk;
  const float* bias = mat ? bv : bqk;
  float* dst        = mat ? vf : qkf;
  int tid = threadIdx.x;
  int tdx = tid & 15;   // 16 groups x 4 cols
  int tsy = tid >> 4;   // 16 groups x 2 rows

  __shared__ float  xs[GBS][GBK + 1];
  __shared__ float4 ws4[GBK][16];

  float acc[2][4];
#pragma unroll
  for (int u = 0; u < 2; ++u)
#pragma unroll
    for (int c = 0; c < 4; ++c) acc[u][c] = 0.f;

  for (int kt = 0; kt < DM; kt += GBK) {
    __syncthreads();
    for (int e = tid; e < GBS * GBK; e += 256) {
      int s = e >> 5, k = e & 31;
      xs[s][k] = x[(sb * GBS + s) * DM + kt + k];
    }
    for (int e = tid; e < GBK * 16; e += 256) {
      int k = e >> 4, d4 = e & 15;
      ws4[k][d4] = ((const float4*)(w + (size_t)(kt + k) * DM + db * 64))[d4];
    }
    __syncthreads();
#pragma unroll 8
    for (int kk = 0; kk < GBK; ++kk) {
      float4 b4 = ws4[kk][tdx];
      float bcol[4] = {b4.x, b4.y, b4.z, b4.w};
#pragma unroll
      for (int u = 0; u < 2; ++u) {
        float a = xs[tsy * 2 + u][kk];
#pragma unroll
        for (int c = 0; c < 4; ++c)
          acc[u][c] = fmaf(a, bcol[c], acc[u][c]);
      }
    }
  }
  int d0 = db * 64 + tdx * 4;
  float4 bb = *(const float4*)(bias + d0);
  float bbv[4] = {bb.x, bb.y, bb.z, bb.w};
  int h = d0 >> 6, dd = d0 & 63;  // db*64 aligns to heads: h = db
#pragma unroll
  for (int u = 0; u < 2; ++u) {
    int s = sb * GBS + tsy * 2 + u;
    float4 o = make_float4(acc[u][0] + bbv[0], acc[u][1] + bbv[1],
                           acc[u][2] + bbv[2], acc[u][3] + bbv[3]);
    *(float4*)(dst + ((size_t)h * S + s) * HD + dd) = o;
  }
}

// ---------------- K2: LSH buckets + ballot-aggregated histogram
__global__ void bucket_kernel(const float* __restrict__ qkf,
                              const float* __restrict__ rot,
                              int* __restrict__ buckets,
                              int* __restrict__ counts) {
  int g = blockIdx.x * blockDim.x + threadIdx.x;
  int n = g & (N - 1);
  int r = g >> 13;
  int h = n >> 10;
  int lane = threadIdx.x & 63;
  const float4* q4 = (const float4*)(qkf + (size_t)n * HD);
  const float* R = rot + (size_t)((r * H + h) * HD) * 8;
  float v[8];
#pragma unroll
  for (int c = 0; c < 8; ++c) v[c] = 0.f;
  for (int d4 = 0; d4 < 16; ++d4) {
    float4 q = q4[d4];
    const float* Rr = R + d4 * 32;
#pragma unroll
    for (int c = 0; c < 8; ++c) v[c] = fmaf(q.x, Rr[c], v[c]);
#pragma unroll
    for (int c = 0; c < 8; ++c) v[c] = fmaf(q.y, Rr[8 + c], v[c]);
#pragma unroll
    for (int c = 0; c < 8; ++c) v[c] = fmaf(q.z, Rr[16 + c], v[c]);
#pragma unroll
    for (int c = 0; c < 8; ++c) v[c] = fmaf(q.w, Rr[24 + c], v[c]);
  }
  float best = v[0];
  int bi = 0;
#pragma unroll
  for (int c = 1; c < 16; ++c) {
    float val = (c < 8) ? v[c] : -v[c - 8];
    if (val > best) { best = val; bi = c; }
  }
  buckets[r * N + n] = bi;
  for (int bk = 0; bk < NB; ++bk) {
    unsigned long long mask = __ballot(bi == bk);
    if (mask && lane == (__ffsll((long long)mask) - 1))
      atomicAdd(&counts[r * NB + bk], __popcll(mask));
  }
}

// ---------------- K3: tiny exclusive scan (128 entries)
__global__ void scan_kernel(const int* __restrict__ counts,
                            int* __restrict__ offsets,
                            int* __restrict__ cursor) {
  int t = threadIdx.x;
  int r = t >> 4, b = t & 15;
  int off = r * N;
  for (int i = 0; i < b; ++i) off += counts[r * NB + i];
  offsets[t] = off;
  cursor[t] = off;
}

// ---------------- K4: scatter, ballot-aggregated (1 atomic per wave-bucket)
__global__ void scatter_kernel(const int* __restrict__ buckets,
                               int* __restrict__ cursor,
                               int* __restrict__ perm) {
  int g = blockIdx.x * blockDim.x + threadIdx.x;
  int n = g & (N - 1);
  int r = g >> 13;
  int lane = threadIdx.x & 63;
  int b = buckets[r * N + n];
  for (int bk = 0; bk < NB; ++bk) {
    unsigned long long mask = __ballot(b == bk);
    if (!mask) continue;
    int leader = __ffsll((long long)mask) - 1;
    int base = 0;
    if (lane == leader) base = atomicAdd(&cursor[r * NB + bk], __popcll(mask));
    base = __shfl(base, leader);
    if (b == bk) {
      int rank = __popcll(mask & ((1ull << lane) - 1ull));
      perm[base + rank] = n;
    }
  }
}

// ---------------- K5: MFMA attention, no-max exp (numerically safe: |s|<~13),
// key-split into NSEG segments per 64-query block. Unnormalized partials go to
// accumR[r][n][64] + denomR[r][n] via atomics; norm_kernel merges rounds.
#define KT 64
#define KST 80   // shorts/row: 160B, 16B-aligned rows, bank-injective b128 reads
#define VST 68   // shorts/row: 136B, 8B-aligned b64 reads
#define NSEG 2
__global__ __launch_bounds__(256) void attn_kernel(
    const float* __restrict__ qkf, const float* __restrict__ vf,
    const int* __restrict__ perm, const int* __restrict__ buckets,
    const int* __restrict__ offsets, const int* __restrict__ counts,
    float* __restrict__ accumR, float* __restrict__ denomR) {
  int blk = blockIdx.x;
  int r = blk >> 8;            // 128 pb x 2 seg per round
  int pb = (blk >> 1) & 127;
  int seg = blk & 1;
  int tid = threadIdx.x;
  int wave = tid >> 6, lane = tid & 63;
  int col = lane & 15, quad = lane >> 4;

  __shared__ short k_lds[KT * KST];
  __shared__ short v_lds[HD * VST];
  __shared__ int sse[2];

  int p = r * N + (pb << 6) + (wave << 4) + col;   // my query column
  int qidx = perm[p];
  int qb = buckets[r * N + qidx];
  int q_start = offsets[r * NB + qb];   // includes r*N base
  int q_end = q_start + counts[r * NB + qb];

  if (tid == 0) sse[0] = q_start;
  if (tid == 255) sse[1] = q_end;
  for (int e = tid; e < HD * VST / 2; e += 256) ((int*)v_lds)[e] = 0;

  // Q fragment: B[k=dim][col=query], lane holds dims s2*32+quad*8+j, SCALE folded
  s16x8 qa[2];
  {
    const float* qp = qkf + (size_t)qidx * HD;
#pragma unroll
    for (int s2 = 0; s2 < 2; ++s2) {
      const float4* q4 = (const float4*)(qp + s2 * 32 + quad * 8);
      float4 u0 = q4[0], u1 = q4[1];
      s16x8 f;
      f[0] = f2bf(u0.x * SCALE); f[1] = f2bf(u0.y * SCALE);
      f[2] = f2bf(u0.z * SCALE); f[3] = f2bf(u0.w * SCALE);
      f[4] = f2bf(u1.x * SCALE); f[5] = f2bf(u1.y * SCALE);
      f[6] = f2bf(u1.z * SCALE); f[7] = f2bf(u1.w * SCALE);
      qa[s2] = f;
    }
  }
  int wbs = __shfl(q_start, 0);
  int wbe = __shfl(q_end, 15);
  __syncthreads();
  int bs = sse[0], be = sse[1];

  float lsum = 0.f;
  f32x4 o0 = {0,0,0,0}, o1 = {0,0,0,0}, o2 = {0,0,0,0}, o3 = {0,0,0,0};

  for (int jt = bs + seg * KT; jt < be; jt += NSEG * KT) {
    int nj = min(KT, be - jt);
    __syncthreads();
    // stage: wave w handles keys w*16..+15; lane reads float2 (coalesced rows)
    for (int j = 0; j < 16; j += 2) {
      int kk = (wave << 4) + j + (lane >> 5);
      int dd = (lane & 31) << 1;
      if (kk < nj) {
        int g = perm[jt + kk];
        float2 kv = *(const float2*)(qkf + (size_t)g * HD + dd);
        float2 vv = *(const float2*)(vf + (size_t)g * HD + dd);
        int c = dd >> 3;   // dim chunk 0..7, xor-swizzled by key
        *(int*)&k_lds[kk * KST + (((c ^ (kk & 7)) << 3) | (dd & 7))] =
            f2bf2(kv.x, kv.y);
        int g0 = kk >> 2;  // key group 0..15, xor-swizzled by dim
        v_lds[dd * VST + (((g0 ^ (dd & 15)) << 2) | (kk & 3))] = f2bf(vv.x);
        v_lds[(dd + 1) * VST + (((g0 ^ ((dd + 1) & 15)) << 2) | (kk & 3))] = f2bf(vv.y);
      }
    }
    __syncthreads();
    if (jt >= wbe || jt + KT <= wbs) continue;
    int c_lo = (wbs > jt) ? ((wbs - jt) >> 4) : 0;
    int c_hi = min(4, (wbe - jt + 15) >> 4);
    for (int c16 = c_lo; c16 < c_hi; ++c16) {
      // S^T chunk: A = K (16 keys x 64 dims), B = Q^T
      f32x4 sacc = {0,0,0,0};
      int key = (c16 << 4) + col;
      const short* kb = &k_lds[key * KST];
#pragma unroll
      for (int s2 = 0; s2 < 2; ++s2) {
        int cr = quad + (s2 << 2);
        s16x8 kf = *(const s16x8*)&kb[((cr ^ (key & 7)) << 3)];
        sacc = __builtin_amdgcn_mfma_f32_16x16x32_bf16(kf, qa[s2], sacc, 0, 0, 0);
      }
      // bucket mask + plain exp (no max tracking needed: |s| bounded ~13)
      int kbase = jt + (c16 << 4) + (quad << 2);
      float pw[4];
#pragma unroll
      for (int u = 0; u < 4; ++u) {
        int pos = kbase + u;
        bool ok = (pos >= q_start) && (pos < q_end);
        pw[u] = ok ? __expf(sacc[u]) : 0.f;
      }
      lsum += (pw[0] + pw[1]) + (pw[2] + pw[3]);
      s16x4 pf;
      pf[0] = f2bf(pw[0]); pf[1] = f2bf(pw[1]);
      pf[2] = f2bf(pw[2]); pf[3] = f2bf(pw[3]);
      int grp = (c16 << 2) + quad;
      // PV: O^T += V^T x P^T (P^T exits QK^T MFMA already in B-layout)
#pragma unroll
      for (int c = 0; c < 4; ++c) {
        int dl = (c << 4) + col;
        s16x4 vfr = *(const s16x4*)&v_lds[dl * VST + ((grp ^ col) << 2)];
        if (c == 0) o0 = MFMA_PV(vfr, pf, o0);
        else if (c == 1) o1 = MFMA_PV(vfr, pf, o1);
        else if (c == 2) o2 = MFMA_PV(vfr, pf, o2);
        else o3 = MFMA_PV(vfr, pf, o3);
      }
    }
  }
  // column sums of P for the denominator
  lsum += __shfl_xor(lsum, 16);
  lsum += __shfl_xor(lsum, 32);
  if (quad == 0) atomicAdd(&denomR[r * N + qidx], lsum);
  float* dst = accumR + ((size_t)r * N + qidx) * HD + (quad << 2);
  f32x4 oarr[4] = {o0, o1, o2, o3};
#pragma unroll
  for (int c = 0; c < 4; ++c)
#pragma unroll
    for (int u = 0; u < 4; ++u)
      atomicAdd(dst + (c << 4) + u, oarr[c][u]);
}

// ---------------- K5b: merge rounds: nrm[n][d] = sum_r accumR[r][n][d]/denomR[r][n]
__global__ __launch_bounds__(256) void norm_kernel(
    const float* __restrict__ accumR, const float* __restrict__ denomR,
    float* __restrict__ nrm) {
  int idx = blockIdx.x * 256 + threadIdx.x;  // N*16
  int n = idx >> 4, d4 = idx & 15;
  float4 s = make_float4(0.f, 0.f, 0.f, 0.f);
#pragma unroll
  for (int r = 0; r < NH; ++r) {
    float inv = 1.f / denomR[r * N + n];
    float4 a = ((const float4*)(accumR + ((size_t)r * N + n) * HD))[d4];
    s.x = fmaf(a.x, inv, s.x);
    s.y = fmaf(a.y, inv, s.y);
    s.z = fmaf(a.z, inv, s.z);
    s.w = fmaf(a.w, inv, s.w);
  }
  ((float4*)(nrm + (size_t)n * HD))[d4] = s;
}

// ---------------- K6: output projection, 32x64 tiles, grid 256
__global__ __launch_bounds__(256) void outproj_kernel(
    const float* __restrict__ nrm, const float* __restrict__ w_o,
    const float* __restrict__ b_o, float* __restrict__ out) {
  int sb = blockIdx.x & 31;
  int db = blockIdx.x >> 5;  // 0..7
  int tid = threadIdx.x;
  int tdx = tid & 15;
  int tsy = tid >> 4;

  __shared__ float  xs[GBS][GBK + 1];
  __shared__ float4 ws4[GBK][16];

  float acc[2][4];
#pragma unroll
  for (int u = 0; u < 2; ++u)
#pragma unroll
    for (int c = 0; c < 4; ++c) acc[u][c] = 0.f;

  for (int kt = 0; kt < DM; kt += GBK) {
    __syncthreads();
    for (int e = tid; e < GBS * GBK; e += 256) {
      int s = e >> 5, k = e & 31;
      int kg = kt + k;
      int h = kg >> 6, dd = kg & 63;
      xs[s][k] = nrm[((size_t)h * S + sb * GBS + s) * HD + dd] * 0.125f;
    }
    for (int e = tid; e < GBK * 16; e += 256) {
      int k = e >> 4, d4 = e & 15;
      ws4[k][d4] = ((const float4*)(w_o + (size_t)(kt + k) * DM + db * 64))[d4];
    }
    __syncthreads();
#pragma unroll 8
    for (int kk = 0; kk < GBK; ++kk) {
      float4 b4 = ws4[kk][tdx];
      float bcol[4] = {b4.x, b4.y, b4.z, b4.w};
#pragma unroll
      for (int u = 0; u < 2; ++u) {
        float a = xs[tsy * 2 + u][kk];
#pragma unroll
        for (int c = 0; c < 4; ++c)
          acc[u][c] = fmaf(a, bcol[c], acc[u][c]);
      }
    }
  }
  int d0 = db * 64 + tdx * 4;
  float4 bb = *(const float4*)(b_o + d0);
  float bbv[4] = {bb.x, bb.y, bb.z, bb.w};
#pragma unroll
  for (int u = 0; u < 2; ++u) {
    int s = sb * GBS + tsy * 2 + u;
    float4 o = make_float4(acc[u][0] + bbv[0], acc[u][1] + bbv[1],
                           acc[u][2] + bbv[2], acc[u][3] + bbv[3]);
    *(float4*)(out + (size_t)s * DM + d0) = o;
  }
}

extern "C" void kernel_launch(void* const* d_in, const int* in_sizes, int n_in,
                              void* d_out, int out_size, void* d_ws, size_t ws_size,
                              hipStream_t stream) {
  const float* x    = (const float*)d_in[0];
  const float* w_qk = (const float*)d_in[1];
  const float* b_qk = (const float*)d_in[2];
  const float* w_v  = (const float*)d_in[3];
  const float* b_v  = (const float*)d_in[4];
  const float* w_o  = (const float*)d_in[5];
  const float* b_o  = (const float*)d_in[6];
  const float* rot  = (const float*)d_in[7];
  float* out = (float*)d_out;

  char* ws = (char*)d_ws;
  const size_t MB = 1024u * 1024u;
  float* qkf    = (float*)(ws);                 // 2 MB
  float* vf     = (float*)(ws + 2 * MB);        // 2 MB
  float* accumR = (float*)(ws + 4 * MB);        // 16 MB (NH*N*HD fp32)
  float* nrm    = (float*)(ws + 20 * MB);       // 2 MB
  float* denomR = (float*)(ws + 22 * MB);       // 256 KB
  int* buckets  = (int*)(ws + 22 * MB + 256u * 1024);   // 256 KB
  int* perm     = (int*)(ws + 22 * MB + 512u * 1024);   // 256 KB
  int* counts   = (int*)(ws + 22 * MB + 768u * 1024);
  int* offsets  = counts + 128;
  int* cursor   = offsets + 128;

  hipMemsetAsync(counts, 0, 128 * sizeof(int), stream);
  hipMemsetAsync(denomR, 0, (size_t)NH * N * sizeof(float), stream);
  hipMemsetAsync(accumR, 0, (size_t)NH * N * HD * sizeof(float), stream);

  proj2_kernel<<<512, 256, 0, stream>>>(x, w_qk, b_qk, w_v, b_v, qkf, vf);
  bucket_kernel<<<(NH * N) / 256, 256, 0, stream>>>(qkf, rot, buckets, counts);
  scan_kernel<<<1, 128, 0, stream>>>(counts, offsets, cursor);
  scatter_kernel<<<(NH * N) / 256, 256, 0, stream>>>(buckets, cursor, perm);
  attn_kernel<<<NH * 128 * NSEG, 256, 0, stream>>>(qkf, vf, perm, buckets,
                                                   offsets, counts, accumR, denomR);
  norm_kernel<<<(N * 16) / 256, 256, 0, stream>>>(accumR, denomR, nrm);
  outproj_kernel<<<256, 256, 0, stream>>>(nrm, w_o, b_o, out);
}

// Round 7
// 326.257 us; speedup vs baseline: 1.3098x; 1.3098x over previous
//
#include <hip/hip_runtime.h>
#include <math.h>

#define S 1024
#define DM 512
#define H 8
#define HD 64
#define NH 8          // n_hashes
#define NB 16         // n_buckets
#define N 8192        // B*H*S
#define SCALE 0.125f  // 1/sqrt(64)

typedef __attribute__((ext_vector_type(4))) float f32x4;
typedef __attribute__((ext_vector_type(8))) short s16x8;
typedef __attribute__((ext_vector_type(4))) short s16x4;

__device__ __forceinline__ short f2bf(float f) {  // RTNE float->bf16
  union { float f; unsigned u; } a; a.f = f;
  unsigned r = a.u + 0x7fffu + ((a.u >> 16) & 1u);
  return (short)(r >> 16);
}
__device__ __forceinline__ int f2bf2(float lo, float hi) {
  return (int)(unsigned short)f2bf(lo) | (((int)f2bf(hi)) << 16);
}

#if __has_builtin(__builtin_amdgcn_mfma_f32_16x16x16_bf16)
#define MFMA_PV(a, b, c) __builtin_amdgcn_mfma_f32_16x16x16_bf16(a, b, c, 0, 0, 0)
#else
#define MFMA_PV(a, b, c) __builtin_amdgcn_mfma_f32_16x16x16bf16_1k(a, b, c, 0, 0, 0)
#endif

// ---------------- K1: fused dual projection GEMM. mat=0 writes fp32 qkf (for
// hashing) + bf16 qkb (for attn); mat=1 writes bf16 vb only.
#define GBS 32
#define GBK 32
__global__ __launch_bounds__(256) void proj2_kernel(
    const float* __restrict__ x,
    const float* __restrict__ wqk, const float* __restrict__ bqk,
    const float* __restrict__ wv,  const float* __restrict__ bv,
    float* __restrict__ qkf, short* __restrict__ qkb, short* __restrict__ vb) {
  int sb  = blockIdx.x & 31;
  int db  = (blockIdx.x >> 5) & 7;  // head
  int mat = blockIdx.x >> 8;        // 0=qk, 1=v
  const float* w    = mat ? wv : wqk;
  const float* bias = mat ? bv : bqk;
  int tid = threadIdx.x;
  int tdx = tid & 15;   // 16 groups x 4 cols
  int tsy = tid >> 4;   // 16 groups x 2 rows

  __shared__ float  xs[GBS][GBK + 1];
  __shared__ float4 ws4[GBK][16];

  float acc[2][4];
#pragma unroll
  for (int u = 0; u < 2; ++u)
#pragma unroll
    for (int c = 0; c < 4; ++c) acc[u][c] = 0.f;

  for (int kt = 0; kt < DM; kt += GBK) {
    __syncthreads();
    for (int e = tid; e < GBS * GBK; e += 256) {
      int s = e >> 5, k = e & 31;
      xs[s][k] = x[(sb * GBS + s) * DM + kt + k];
    }
    for (int e = tid; e < GBK * 16; e += 256) {
      int k = e >> 4, d4 = e & 15;
      ws4[k][d4] = ((const float4*)(w + (size_t)(kt + k) * DM + db * 64))[d4];
    }
    __syncthreads();
#pragma unroll 8
    for (int kk = 0; kk < GBK; ++kk) {
      float4 b4 = ws4[kk][tdx];
      float bcol[4] = {b4.x, b4.y, b4.z, b4.w};
#pragma unroll
      for (int u = 0; u < 2; ++u) {
        float a = xs[tsy * 2 + u][kk];
#pragma unroll
        for (int c = 0; c < 4; ++c)
          acc[u][c] = fmaf(a, bcol[c], acc[u][c]);
      }
    }
  }
  int dd = tdx * 4;  // head-local dim
  float4 bb = *(const float4*)(bias + db * 64 + dd);
  float bbv[4] = {bb.x, bb.y, bb.z, bb.w};
#pragma unroll
  for (int u = 0; u < 2; ++u) {
    int s = sb * GBS + tsy * 2 + u;
    size_t row = (size_t)db * S + s;
    float o0 = acc[u][0] + bbv[0], o1 = acc[u][1] + bbv[1];
    float o2 = acc[u][2] + bbv[2], o3 = acc[u][3] + bbv[3];
    int2 pk = make_int2(f2bf2(o0, o1), f2bf2(o2, o3));
    if (mat == 0) {
      *(float4*)(qkf + row * HD + dd) = make_float4(o0, o1, o2, o3);
      *(int2*)(qkb + row * HD + dd) = pk;
    } else {
      *(int2*)(vb + row * HD + dd) = pk;
    }
  }
}

// ---------------- K2: LSH buckets + ballot-aggregated histogram
__global__ void bucket_kernel(const float* __restrict__ qkf,
                              const float* __restrict__ rot,
                              int* __restrict__ buckets,
                              int* __restrict__ counts) {
  int g = blockIdx.x * blockDim.x + threadIdx.x;
  int n = g & (N - 1);
  int r = g >> 13;
  int h = n >> 10;
  int lane = threadIdx.x & 63;
  const float4* q4 = (const float4*)(qkf + (size_t)n * HD);
  const float* R = rot + (size_t)((r * H + h) * HD) * 8;
  float v[8];
#pragma unroll
  for (int c = 0; c < 8; ++c) v[c] = 0.f;
  for (int d4 = 0; d4 < 16; ++d4) {
    float4 q = q4[d4];
    const float* Rr = R + d4 * 32;
#pragma unroll
    for (int c = 0; c < 8; ++c) v[c] = fmaf(q.x, Rr[c], v[c]);
#pragma unroll
    for (int c = 0; c < 8; ++c) v[c] = fmaf(q.y, Rr[8 + c], v[c]);
#pragma unroll
    for (int c = 0; c < 8; ++c) v[c] = fmaf(q.z, Rr[16 + c], v[c]);
#pragma unroll
    for (int c = 0; c < 8; ++c) v[c] = fmaf(q.w, Rr[24 + c], v[c]);
  }
  float best = v[0];
  int bi = 0;
#pragma unroll
  for (int c = 1; c < 16; ++c) {
    float val = (c < 8) ? v[c] : -v[c - 8];
    if (val > best) { best = val; bi = c; }
  }
  buckets[r * N + n] = bi;
  for (int bk = 0; bk < NB; ++bk) {
    unsigned long long mask = __ballot(bi == bk);
    if (mask && lane == (__ffsll((long long)mask) - 1))
      atomicAdd(&counts[r * NB + bk], __popcll(mask));
  }
}

// ---------------- K3: scatter with fused scan (offsets computed in-block);
// block 0 publishes offsets[] for attn. cursor[] is zero-initialized.
__global__ __launch_bounds__(256) void scatter_kernel(
    const int* __restrict__ buckets, const int* __restrict__ counts,
    int* __restrict__ cursor, int* __restrict__ offsets,
    int* __restrict__ perm) {
  __shared__ int cnt_s[128];
  __shared__ int off_s[128];
  int tid = threadIdx.x;
  if (tid < 128) cnt_s[tid] = counts[tid];
  __syncthreads();
  if (tid < 128) {
    int r = tid >> 4, b = tid & 15;
    int off = r * N;
    for (int i = 0; i < b; ++i) off += cnt_s[(r << 4) + i];
    off_s[tid] = off;
    if (blockIdx.x == 0) offsets[tid] = off;
  }
  __syncthreads();
  int g = blockIdx.x * 256 + tid;
  int n = g & (N - 1);
  int r = g >> 13;
  int lane = tid & 63;
  int b = buckets[r * N + n];
  for (int bk = 0; bk < NB; ++bk) {
    unsigned long long mask = __ballot(b == bk);
    if (!mask) continue;
    int leader = __ffsll((long long)mask) - 1;
    int base = 0;
    if (lane == leader) base = atomicAdd(&cursor[(r << 4) + bk], __popcll(mask));
    base = __shfl(base, leader);
    if (b == bk) {
      int rank = __popcll(mask & ((1ull << lane) - 1ull));
      perm[off_s[(r << 4) + bk] + base + rank] = n;
    }
  }
}

// ---------------- K4: MFMA attention, bf16 inputs, double-buffered LDS with
// ONE barrier per 64-key tile, no-max exp (|s| bounded ~13 -> fp32-safe).
// r5-verified swizzles: KST=72 (store granule cs = csk^(jsk&3), read
// cidx = ((s2<<1)+(quad>>1))^(key&3)); VST=66 (store (jh^(d&3))<<2 | jl,
// read ((grp)^(col&3) undone via grp^(col&3)) -- copied verbatim.
#define KT 64
#define KST 72
#define VST 66
__global__ __launch_bounds__(256) void attn_kernel(
    const short* __restrict__ qkb, const short* __restrict__ vb,
    const int* __restrict__ perm, const int* __restrict__ buckets,
    const int* __restrict__ offsets, const int* __restrict__ counts,
    float* __restrict__ accum) {
  int r = blockIdx.x >> 7;
  int pb = blockIdx.x & 127;
  int tid = threadIdx.x;
  int wave = tid >> 6, lane = tid & 63;
  int col = lane & 15, quad = lane >> 4;

  __shared__ short k_lds[2][KT * KST];
  __shared__ short v_lds[2][HD * VST];
  __shared__ int sse[2];

  int p = r * N + (pb << 6) + (wave << 4) + col;   // my query column
  int qidx = perm[p];
  int qb = buckets[r * N + qidx];
  int q_start = offsets[r * NB + qb];   // includes r*N base
  int q_end = q_start + counts[r * NB + qb];

  if (tid == 0) sse[0] = q_start;
  if (tid == 255) sse[1] = q_end;
  // zero both V buffers (guards 0*NaN on masked stale lanes of first tiles)
  for (int e = tid; e < HD * VST; e += 256) ((int*)v_lds)[e] = 0;

  // Q fragment: direct bf16 load, dims s2*32 + quad*8 .. +7
  s16x8 qa[2];
#pragma unroll
  for (int s2 = 0; s2 < 2; ++s2)
    qa[s2] = *(const s16x8*)(qkb + (size_t)qidx * HD + s2 * 32 + quad * 8);

  int wbs = __shfl(q_start, 0);
  int wbe = __shfl(q_end, 15);
  __syncthreads();
  int bs = sse[0], be = sse[1];

  float lsum = 0.f;
  f32x4 o0 = {0,0,0,0}, o1 = {0,0,0,0}, o2 = {0,0,0,0}, o3 = {0,0,0,0};

  int jsk = tid >> 2, csk = tid & 3;   // stager: key slot, 16-dim chunk
  int jh = jsk >> 2, jl = jsk & 3;
  int kgran = jsk * KST + ((csk ^ (jsk & 3)) << 4);

  // stage tile 0 into buffer 0
  {
    int nj = min(KT, be - bs);
    if (jsk < nj) {
      int g = perm[bs + jsk];
      const s16x8* kp = (const s16x8*)(qkb + (size_t)g * HD + (csk << 4));
      s16x8 a0 = kp[0], a1 = kp[1];
      const s16x8* vp = (const s16x8*)(vb + (size_t)g * HD + (csk << 4));
      s16x8 b0 = vp[0], b1 = vp[1];
      s16x8* kd = (s16x8*)&k_lds[0][kgran];
      kd[0] = a0; kd[1] = a1;
#pragma unroll
      for (int t = 0; t < 8; ++t) {
        int d = (csk << 4) + t;
        v_lds[0][d * VST + (((jh ^ (t & 3)) << 2) | jl)] = b0[t];
      }
#pragma unroll
      for (int t = 8; t < 16; ++t) {
        int d = (csk << 4) + t;
        v_lds[0][d * VST + (((jh ^ (t & 3)) << 2) | jl)] = b1[t - 8];
      }
    }
  }
  __syncthreads();

  int ntiles = (be - bs + KT - 1) >> 6;
  for (int t = 0; t < ntiles; ++t) {
    int jt = bs + (t << 6);
    int cur = t & 1, nxt = cur ^ 1;
    // prefetch tile t+1 into registers (overlaps with compute below)
    s16x8 a0, a1, b0, b1;
    bool pf_ok = false;
    int jn = jt + KT;
    if (jn < be) {
      int njn = min(KT, be - jn);
      if (jsk < njn) {
        pf_ok = true;
        int g = perm[jn + jsk];
        const s16x8* kp = (const s16x8*)(qkb + (size_t)g * HD + (csk << 4));
        a0 = kp[0]; a1 = kp[1];
        const s16x8* vp = (const s16x8*)(vb + (size_t)g * HD + (csk << 4));
        b0 = vp[0]; b1 = vp[1];
      }
    }
    // compute tile t from buffer cur
    if (jt < wbe && jt + KT > wbs) {
      int c_lo = (wbs > jt) ? ((wbs - jt) >> 4) : 0;
      int c_hi = min(4, (wbe - jt + 15) >> 4);
      for (int c16 = c_lo; c16 < c_hi; ++c16) {
        f32x4 sacc = {0,0,0,0};
        int key = (c16 << 4) + col;
        const short* kb = &k_lds[cur][key * KST];
#pragma unroll
        for (int s2 = 0; s2 < 2; ++s2) {
          int cidx = ((s2 << 1) + (quad >> 1)) ^ (key & 3);
          s16x8 kf = *(const s16x8*)&kb[(cidx << 4) + ((quad & 1) << 3)];
          sacc = __builtin_amdgcn_mfma_f32_16x16x32_bf16(kf, qa[s2], sacc, 0, 0, 0);
        }
        int kbase = jt + (c16 << 4) + (quad << 2);
        float pw[4];
#pragma unroll
        for (int u = 0; u < 4; ++u) {
          int pos = kbase + u;
          bool ok = (pos >= q_start) && (pos < q_end);
          pw[u] = ok ? __expf(sacc[u] * SCALE) : 0.f;
        }
        lsum += (pw[0] + pw[1]) + (pw[2] + pw[3]);
        s16x4 pf;
        pf[0] = f2bf(pw[0]); pf[1] = f2bf(pw[1]);
        pf[2] = f2bf(pw[2]); pf[3] = f2bf(pw[3]);
#pragma unroll
        for (int c = 0; c < 4; ++c) {
          int dl = (c << 4) + col;
          int grp = ((c16 << 2) + quad) ^ (col & 3);
          int off = dl * VST + (grp << 2);
          int lo_ = *(const int*)&v_lds[cur][off];
          int hi_ = *(const int*)&v_lds[cur][off + 2];
          s16x4 vfr;
          vfr[0] = (short)(lo_ & 0xffff); vfr[1] = (short)(lo_ >> 16);
          vfr[2] = (short)(hi_ & 0xffff); vfr[3] = (short)(hi_ >> 16);
          if (c == 0) o0 = MFMA_PV(vfr, pf, o0);
          else if (c == 1) o1 = MFMA_PV(vfr, pf, o1);
          else if (c == 2) o2 = MFMA_PV(vfr, pf, o2);
          else o3 = MFMA_PV(vfr, pf, o3);
        }
      }
    }
    // write prefetched tile into buffer nxt
    if (pf_ok) {
      s16x8* kd = (s16x8*)&k_lds[nxt][kgran];
      kd[0] = a0; kd[1] = a1;
#pragma unroll
      for (int u = 0; u < 8; ++u) {
        int d = (csk << 4) + u;
        v_lds[nxt][d * VST + (((jh ^ (u & 3)) << 2) | jl)] = b0[u];
      }
#pragma unroll
      for (int u = 8; u < 16; ++u) {
        int d = (csk << 4) + u;
        v_lds[nxt][d * VST + (((jh ^ (u & 3)) << 2) | jl)] = b1[u - 8];
      }
    }
    __syncthreads();
  }

  lsum += __shfl_xor(lsum, 16);
  lsum += __shfl_xor(lsum, 32);
  float inv = 1.f / lsum;
  float* dst = accum + (size_t)qidx * HD + (quad << 2);
  f32x4 oarr[4] = {o0, o1, o2, o3};
#pragma unroll
  for (int c = 0; c < 4; ++c)
#pragma unroll
    for (int u = 0; u < 4; ++u)
      atomicAdd(dst + (c << 4) + u, oarr[c][u] * inv);
}

// ---------------- K5: output projection, 32x64 tiles, grid 256
__global__ __launch_bounds__(256) void outproj_kernel(
    const float* __restrict__ accum, const float* __restrict__ w_o,
    const float* __restrict__ b_o, float* __restrict__ out) {
  int sb = blockIdx.x & 31;
  int db = blockIdx.x >> 5;  // 0..7
  int tid = threadIdx.x;
  int tdx = tid & 15;
  int tsy = tid >> 4;

  __shared__ float  xs[GBS][GBK + 1];
  __shared__ float4 ws4[GBK][16];

  float acc[2][4];
#pragma unroll
  for (int u = 0; u < 2; ++u)
#pragma unroll
    for (int c = 0; c < 4; ++c) acc[u][c] = 0.f;

  for (int kt = 0; kt < DM; kt += GBK) {
    __syncthreads();
    for (int e = tid; e < GBS * GBK; e += 256) {
      int s = e >> 5, k = e & 31;
      int kg = kt + k;
      int h = kg >> 6, dd = kg & 63;
      xs[s][k] = accum[((size_t)h * S + sb * GBS + s) * HD + dd] * 0.125f;
    }
    for (int e = tid; e < GBK * 16; e += 256) {
      int k = e >> 4, d4 = e & 15;
      ws4[k][d4] = ((const float4*)(w_o + (size_t)(kt + k) * DM + db * 64))[d4];
    }
    __syncthreads();
#pragma unroll 8
    for (int kk = 0; kk < GBK; ++kk) {
      float4 b4 = ws4[kk][tdx];
      float bcol[4] = {b4.x, b4.y, b4.z, b4.w};
#pragma unroll
      for (int u = 0; u < 2; ++u) {
        float a = xs[tsy * 2 + u][kk];
#pragma unroll
        for (int c = 0; c < 4; ++c)
          acc[u][c] = fmaf(a, bcol[c], acc[u][c]);
      }
    }
  }
  int d0 = db * 64 + tdx * 4;
  float4 bb = *(const float4*)(b_o + d0);
  float bbv[4] = {bb.x, bb.y, bb.z, bb.w};
#pragma unroll
  for (int u = 0; u < 2; ++u) {
    int s = sb * GBS + tsy * 2 + u;
    float4 o = make_float4(acc[u][0] + bbv[0], acc[u][1] + bbv[1],
                           acc[u][2] + bbv[2], acc[u][3] + bbv[3]);
    *(float4*)(out + (size_t)s * DM + d0) = o;
  }
}

extern "C" void kernel_launch(void* const* d_in, const int* in_sizes, int n_in,
                              void* d_out, int out_size, void* d_ws, size_t ws_size,
                              hipStream_t stream) {
  const float* x    = (const float*)d_in[0];
  const float* w_qk = (const float*)d_in[1];
  const float* b_qk = (const float*)d_in[2];
  const float* w_v  = (const float*)d_in[3];
  const float* b_v  = (const float*)d_in[4];
  const float* w_o  = (const float*)d_in[5];
  const float* b_o  = (const float*)d_in[6];
  const float* rot  = (const float*)d_in[7];
  float* out = (float*)d_out;

  char* ws = (char*)d_ws;
  const size_t MB = 1024u * 1024u;
  float* qkf    = (float*)(ws);                 // 2 MB fp32 (hashing)
  short* qkb    = (short*)(ws + 2 * MB);        // 1 MB bf16
  short* vb     = (short*)(ws + 3 * MB);        // 1 MB bf16
  float* accum  = (float*)(ws + 4 * MB);        // 2 MB
  int* buckets  = (int*)(ws + 6 * MB);          // 256 KB
  int* perm     = (int*)(ws + 6 * MB + 256u * 1024);  // 256 KB
  int* counts   = (int*)(ws + 6 * MB + 512u * 1024);  // 128 ints
  int* cursor   = counts + 128;                        // 128 ints
  int* offsets  = cursor + 128;                        // 128 ints

  hipMemsetAsync(counts, 0, 256 * sizeof(int), stream);  // counts + cursor
  hipMemsetAsync(accum, 0, (size_t)N * HD * sizeof(float), stream);

  proj2_kernel<<<512, 256, 0, stream>>>(x, w_qk, b_qk, w_v, b_v, qkf, qkb, vb);
  bucket_kernel<<<(NH * N) / 256, 256, 0, stream>>>(qkf, rot, buckets, counts);
  scatter_kernel<<<(NH * N) / 256, 256, 0, stream>>>(buckets, counts, cursor,
                                                     offsets, perm);
  attn_kernel<<<NH * 128, 256, 0, stream>>>(qkb, vb, perm, buckets,
                                            offsets, counts, accum);
  outproj_kernel<<<256, 256, 0, stream>>>(accum, w_o, b_o, out);
}

// Round 8
// 299.944 us; speedup vs baseline: 1.4247x; 1.0877x over previous
//
#include <hip/hip_runtime.h>
#include <math.h>

#define S 1024
#define DM 512
#define H 8
#define HD 64
#define NH 8          // n_hashes
#define NB 16         // n_buckets
#define N 8192        // B*H*S
#define SCALE 0.125f  // 1/sqrt(64)

typedef __attribute__((ext_vector_type(4))) float f32x4;
typedef __attribute__((ext_vector_type(8))) short s16x8;
typedef __attribute__((ext_vector_type(4))) short s16x4;

__device__ __forceinline__ short f2bf(float f) {  // RTNE float->bf16
  union { float f; unsigned u; } a; a.f = f;
  unsigned r = a.u + 0x7fffu + ((a.u >> 16) & 1u);
  return (short)(r >> 16);
}
__device__ __forceinline__ int f2bf2(float lo, float hi) {
  return (int)(unsigned short)f2bf(lo) | (((int)f2bf(hi)) << 16);
}

#if __has_builtin(__builtin_amdgcn_mfma_f32_16x16x16_bf16)
#define MFMA_PV(a, b, c) __builtin_amdgcn_mfma_f32_16x16x16_bf16(a, b, c, 0, 0, 0)
#else
#define MFMA_PV(a, b, c) __builtin_amdgcn_mfma_f32_16x16x16bf16_1k(a, b, c, 0, 0, 0)
#endif

// ---------------- K1: fused dual projection GEMM. mat=0 writes fp32 qkf (for
// hashing) + bf16 qkb; mat=1 writes bf16 vb. Block 0 zeroes counts+cursor.
#define GBS 32
#define GBK 32
__global__ __launch_bounds__(256) void proj2_kernel(
    const float* __restrict__ x,
    const float* __restrict__ wqk, const float* __restrict__ bqk,
    const float* __restrict__ wv,  const float* __restrict__ bv,
    float* __restrict__ qkf, short* __restrict__ qkb, short* __restrict__ vb,
    int* __restrict__ cz) {
  int sb  = blockIdx.x & 31;
  int db  = (blockIdx.x >> 5) & 7;  // head
  int mat = blockIdx.x >> 8;        // 0=qk, 1=v
  const float* w    = mat ? wv : wqk;
  const float* bias = mat ? bv : bqk;
  int tid = threadIdx.x;
  if (blockIdx.x == 0) cz[tid] = 0;   // counts[128] + cursor[128]
  int tdx = tid & 15;   // 16 groups x 4 cols
  int tsy = tid >> 4;   // 16 groups x 2 rows

  __shared__ float  xs[GBS][GBK + 1];
  __shared__ float4 ws4[GBK][16];

  float acc[2][4];
#pragma unroll
  for (int u = 0; u < 2; ++u)
#pragma unroll
    for (int c = 0; c < 4; ++c) acc[u][c] = 0.f;

  for (int kt = 0; kt < DM; kt += GBK) {
    __syncthreads();
    for (int e = tid; e < GBS * GBK; e += 256) {
      int s = e >> 5, k = e & 31;
      xs[s][k] = x[(sb * GBS + s) * DM + kt + k];
    }
    for (int e = tid; e < GBK * 16; e += 256) {
      int k = e >> 4, d4 = e & 15;
      ws4[k][d4] = ((const float4*)(w + (size_t)(kt + k) * DM + db * 64))[d4];
    }
    __syncthreads();
#pragma unroll 8
    for (int kk = 0; kk < GBK; ++kk) {
      float4 b4 = ws4[kk][tdx];
      float bcol[4] = {b4.x, b4.y, b4.z, b4.w};
#pragma unroll
      for (int u = 0; u < 2; ++u) {
        float a = xs[tsy * 2 + u][kk];
#pragma unroll
        for (int c = 0; c < 4; ++c)
          acc[u][c] = fmaf(a, bcol[c], acc[u][c]);
      }
    }
  }
  int dd = tdx * 4;  // head-local dim
  float4 bb = *(const float4*)(bias + db * 64 + dd);
  float bbv[4] = {bb.x, bb.y, bb.z, bb.w};
#pragma unroll
  for (int u = 0; u < 2; ++u) {
    int s = sb * GBS + tsy * 2 + u;
    size_t row = (size_t)db * S + s;
    float o0 = acc[u][0] + bbv[0], o1 = acc[u][1] + bbv[1];
    float o2 = acc[u][2] + bbv[2], o3 = acc[u][3] + bbv[3];
    int2 pk = make_int2(f2bf2(o0, o1), f2bf2(o2, o3));
    if (mat == 0) {
      *(float4*)(qkf + row * HD + dd) = make_float4(o0, o1, o2, o3);
      *(int2*)(qkb + row * HD + dd) = pk;
    } else {
      *(int2*)(vb + row * HD + dd) = pk;
    }
  }
}

// ---------------- K2: LSH buckets + ballot-aggregated histogram
__global__ void bucket_kernel(const float* __restrict__ qkf,
                              const float* __restrict__ rot,
                              int* __restrict__ buckets,
                              int* __restrict__ counts) {
  int g = blockIdx.x * blockDim.x + threadIdx.x;
  int n = g & (N - 1);
  int r = g >> 13;
  int h = n >> 10;
  int lane = threadIdx.x & 63;
  const float4* q4 = (const float4*)(qkf + (size_t)n * HD);
  const float* R = rot + (size_t)((r * H + h) * HD) * 8;
  float v[8];
#pragma unroll
  for (int c = 0; c < 8; ++c) v[c] = 0.f;
  for (int d4 = 0; d4 < 16; ++d4) {
    float4 q = q4[d4];
    const float* Rr = R + d4 * 32;
#pragma unroll
    for (int c = 0; c < 8; ++c) v[c] = fmaf(q.x, Rr[c], v[c]);
#pragma unroll
    for (int c = 0; c < 8; ++c) v[c] = fmaf(q.y, Rr[8 + c], v[c]);
#pragma unroll
    for (int c = 0; c < 8; ++c) v[c] = fmaf(q.z, Rr[16 + c], v[c]);
#pragma unroll
    for (int c = 0; c < 8; ++c) v[c] = fmaf(q.w, Rr[24 + c], v[c]);
  }
  float best = v[0];
  int bi = 0;
#pragma unroll
  for (int c = 1; c < 16; ++c) {
    float val = (c < 8) ? v[c] : -v[c - 8];
    if (val > best) { best = val; bi = c; }
  }
  buckets[r * N + n] = bi;
  for (int bk = 0; bk < NB; ++bk) {
    unsigned long long mask = __ballot(bi == bk);
    if (mask && lane == (__ffsll((long long)mask) - 1))
      atomicAdd(&counts[r * NB + bk], __popcll(mask));
  }
}

// ---------------- K3: scatter with fused scan; block 0 publishes offsets[]
__global__ __launch_bounds__(256) void scatter_kernel(
    const int* __restrict__ buckets, const int* __restrict__ counts,
    int* __restrict__ cursor, int* __restrict__ offsets,
    int* __restrict__ perm) {
  __shared__ int cnt_s[128];
  __shared__ int off_s[128];
  int tid = threadIdx.x;
  if (tid < 128) cnt_s[tid] = counts[tid];
  __syncthreads();
  if (tid < 128) {
    int r = tid >> 4, b = tid & 15;
    int off = r * N;
    for (int i = 0; i < b; ++i) off += cnt_s[(r << 4) + i];
    off_s[tid] = off;
    if (blockIdx.x == 0) offsets[tid] = off;
  }
  __syncthreads();
  int g = blockIdx.x * 256 + tid;
  int n = g & (N - 1);
  int r = g >> 13;
  int lane = tid & 63;
  int b = buckets[r * N + n];
  for (int bk = 0; bk < NB; ++bk) {
    unsigned long long mask = __ballot(b == bk);
    if (!mask) continue;
    int leader = __ffsll((long long)mask) - 1;
    int base = 0;
    if (lane == leader) base = atomicAdd(&cursor[(r << 4) + bk], __popcll(mask));
    base = __shfl(base, leader);
    if (b == bk) {
      int rank = __popcll(mask & ((1ull << lane) - 1ull));
      perm[off_s[(r << 4) + bk] + base + rank] = n;
    }
  }
}

// ---------------- K4: MFMA attention. 512 threads = 8 waves x 16 queries.
// S^T = K x Q^T (mfma 16x16x32; C: col=query, row=key). That C-layout is the
// A-operand layout of P (m=query, k=key), so O = P x V with V staged in
// NATURAL [key][dim] rows (b128 writes, no transpose). One block owns each
// (round, query) fully -> plain normalized stores, no atomics.
#define KT 64
#define KST 72
#define VST 72
__global__ __launch_bounds__(512) void attn_kernel(
    const short* __restrict__ qkb, const short* __restrict__ vb,
    const int* __restrict__ perm, const int* __restrict__ buckets,
    const int* __restrict__ offsets, const int* __restrict__ counts,
    float* __restrict__ accumR) {
  int r = blockIdx.x >> 6;
  int pb = blockIdx.x & 63;
  int tid = threadIdx.x;
  int wave = tid >> 6, lane = tid & 63;
  int col = lane & 15, quad = lane >> 4;

  __shared__ short k_lds[2][KT * KST];
  __shared__ short v_lds[2][KT * VST];
  __shared__ int sse[2];

  int p = r * N + (pb << 7) + (wave << 4) + col;   // my query (sorted slot)
  int qidx = perm[p];
  int qb = buckets[r * N + qidx];
  int q_start = offsets[r * NB + qb];   // includes r*N base
  int q_end = q_start + counts[r * NB + qb];

  if (tid == 0) sse[0] = q_start;
  if (tid == 511) sse[1] = q_end;
  // zero both V buffers (guards 0*garbage on first tiles' stale lanes)
  for (int e = tid; e < KT * VST; e += 512) ((int*)v_lds)[e] = 0;

  // Q fragment: B[k=dim][n=query], lane holds dims s2*32 + quad*8 .. +7
  s16x8 qa[2];
#pragma unroll
  for (int s2 = 0; s2 < 2; ++s2)
    qa[s2] = *(const s16x8*)(qkb + (size_t)qidx * HD + s2 * 32 + quad * 8);

  int wbs = __shfl(q_start, 0);
  int wbe = __shfl(q_end, 15);
  __syncthreads();
  int bs = sse[0], be = sse[1];

  float lsum = 0.f;
  f32x4 o0 = {0,0,0,0}, o1 = {0,0,0,0}, o2 = {0,0,0,0}, o3 = {0,0,0,0};

  int jsk = tid >> 2, csk = tid & 3;   // stager: key slot, 16-dim chunk
  bool stager = tid < 256;
  int kgran = jsk * KST + ((csk ^ (jsk & 3)) << 4);  // r5-verified K swizzle
  int vgran = jsk * VST + (csk << 4);                // natural V rows

  {  // stage tile 0 into buffer 0
    int nj = min(KT, be - bs);
    if (stager && jsk < nj) {
      int g = perm[bs + jsk];
      const s16x8* kp = (const s16x8*)(qkb + (size_t)g * HD + (csk << 4));
      const s16x8* vp = (const s16x8*)(vb + (size_t)g * HD + (csk << 4));
      s16x8 a0 = kp[0], a1 = kp[1], b0 = vp[0], b1 = vp[1];
      s16x8* kd = (s16x8*)&k_lds[0][kgran];
      kd[0] = a0; kd[1] = a1;
      s16x8* vd = (s16x8*)&v_lds[0][vgran];
      vd[0] = b0; vd[1] = b1;
    }
  }
  __syncthreads();

  int ntiles = (be - bs + KT - 1) >> 6;
  for (int t = 0; t < ntiles; ++t) {
    int jt = bs + (t << 6);
    int cur = t & 1, nxt = cur ^ 1;
    // prefetch tile t+1 into registers (overlaps compute)
    s16x8 a0, a1, b0, b1;
    bool pf_ok = false;
    int jn = jt + KT;
    if (jn < be && stager) {
      int njn = min(KT, be - jn);
      if (jsk < njn) {
        pf_ok = true;
        int g = perm[jn + jsk];
        const s16x8* kp = (const s16x8*)(qkb + (size_t)g * HD + (csk << 4));
        const s16x8* vp = (const s16x8*)(vb + (size_t)g * HD + (csk << 4));
        a0 = kp[0]; a1 = kp[1]; b0 = vp[0]; b1 = vp[1];
      }
    }
    // compute tile t from buffer cur
    if (jt < wbe && jt + KT > wbs) {
      int c_lo = (wbs > jt) ? ((wbs - jt) >> 4) : 0;
      int c_hi = min(4, (wbe - jt + 15) >> 4);
      for (int c16 = c_lo; c16 < c_hi; ++c16) {
        f32x4 sacc = {0,0,0,0};
        int key = (c16 << 4) + col;
        const short* kb = &k_lds[cur][key * KST];
#pragma unroll
        for (int s2 = 0; s2 < 2; ++s2) {
          int cidx = ((s2 << 1) + (quad >> 1)) ^ (key & 3);
          s16x8 kf = *(const s16x8*)&kb[(cidx << 4) + ((quad & 1) << 3)];
          sacc = __builtin_amdgcn_mfma_f32_16x16x32_bf16(kf, qa[s2], sacc, 0, 0, 0);
        }
        // mask by query col's bucket range; plain exp (|s| bounded ~13)
        int kbase = jt + (c16 << 4) + (quad << 2);
        float pw[4];
#pragma unroll
        for (int u = 0; u < 4; ++u) {
          int pos = kbase + u;
          bool ok = (pos >= q_start) && (pos < q_end);
          pw[u] = ok ? __expf(sacc[u] * SCALE) : 0.f;
        }
        lsum += (pw[0] + pw[1]) + (pw[2] + pw[3]);
        s16x4 pfr;
        pfr[0] = f2bf(pw[0]); pfr[1] = f2bf(pw[1]);
        pfr[2] = f2bf(pw[2]); pfr[3] = f2bf(pw[3]);
        // O = P x V: B-operand = V[key=quad*4+j][dim=c*16+col], natural rows
        const short* vbp = &v_lds[cur][((c16 << 4) + (quad << 2)) * VST + col];
#pragma unroll
        for (int c = 0; c < 4; ++c) {
          s16x4 vfr;
#pragma unroll
          for (int j = 0; j < 4; ++j)
            vfr[j] = vbp[j * VST + (c << 4)];
          if (c == 0) o0 = MFMA_PV(pfr, vfr, o0);
          else if (c == 1) o1 = MFMA_PV(pfr, vfr, o1);
          else if (c == 2) o2 = MFMA_PV(pfr, vfr, o2);
          else o3 = MFMA_PV(pfr, vfr, o3);
        }
      }
    }
    // write prefetched tile into buffer nxt
    if (pf_ok) {
      s16x8* kd = (s16x8*)&k_lds[nxt][kgran];
      kd[0] = a0; kd[1] = a1;
      s16x8* vd = (s16x8*)&v_lds[nxt][vgran];
      vd[0] = b0; vd[1] = b1;
    }
    __syncthreads();
  }

  // denominator per query=col, then redistribute to D-layout rows
  lsum += __shfl_xor(lsum, 16);
  lsum += __shfl_xor(lsum, 32);
  float inv = 1.f / lsum;
#pragma unroll
  for (int u = 0; u < 4; ++u) {
    int slot = (quad << 2) + u;          // query slot owning O row quad*4+u
    float inv_u = __shfl(inv, slot);
    int qidx_u = __shfl(qidx, slot);
    float* dst = accumR + ((size_t)r * N + qidx_u) * HD + col;
    dst[0]  = o0[u] * inv_u;
    dst[16] = o1[u] * inv_u;
    dst[32] = o2[u] * inv_u;
    dst[48] = o3[u] * inv_u;
  }
}

// ---------------- K5: output projection; x-staging sums the 8 rounds
__global__ __launch_bounds__(256) void outproj_kernel(
    const float* __restrict__ accumR, const float* __restrict__ w_o,
    const float* __restrict__ b_o, float* __restrict__ out) {
  int sb = blockIdx.x & 31;
  int db = blockIdx.x >> 5;  // 0..7
  int tid = threadIdx.x;
  int tdx = tid & 15;
  int tsy = tid >> 4;

  __shared__ float  xs[GBS][GBK + 1];
  __shared__ float4 ws4[GBK][16];

  float acc[2][4];
#pragma unroll
  for (int u = 0; u < 2; ++u)
#pragma unroll
    for (int c = 0; c < 4; ++c) acc[u][c] = 0.f;

  for (int kt = 0; kt < DM; kt += GBK) {
    __syncthreads();
    for (int e = tid; e < GBS * GBK; e += 256) {
      int s = e >> 5, k = e & 31;
      int kg = kt + k;
      int h = kg >> 6, dd = kg & 63;
      int n = h * S + sb * GBS + s;
      float sum = 0.f;
#pragma unroll
      for (int rr = 0; rr < NH; ++rr)
        sum += accumR[((size_t)rr * N + n) * HD + dd];
      xs[s][k] = sum * 0.125f;
    }
    for (int e = tid; e < GBK * 16; e += 256) {
      int k = e >> 4, d4 = e & 15;
      ws4[k][d4] = ((const float4*)(w_o + (size_t)(kt + k) * DM + db * 64))[d4];
    }
    __syncthreads();
#pragma unroll 8
    for (int kk = 0; kk < GBK; ++kk) {
      float4 b4 = ws4[kk][tdx];
      float bcol[4] = {b4.x, b4.y, b4.z, b4.w};
#pragma unroll
      for (int u = 0; u < 2; ++u) {
        float a = xs[tsy * 2 + u][kk];
#pragma unroll
        for (int c = 0; c < 4; ++c)
          acc[u][c] = fmaf(a, bcol[c], acc[u][c]);
      }
    }
  }
  int d0 = db * 64 + tdx * 4;
  float4 bb = *(const float4*)(b_o + d0);
  float bbv[4] = {bb.x, bb.y, bb.z, bb.w};
#pragma unroll
  for (int u = 0; u < 2; ++u) {
    int s = sb * GBS + tsy * 2 + u;
    float4 o = make_float4(acc[u][0] + bbv[0], acc[u][1] + bbv[1],
                           acc[u][2] + bbv[2], acc[u][3] + bbv[3]);
    *(float4*)(out + (size_t)s * DM + d0) = o;
  }
}

extern "C" void kernel_launch(void* const* d_in, const int* in_sizes, int n_in,
                              void* d_out, int out_size, void* d_ws, size_t ws_size,
                              hipStream_t stream) {
  const float* x    = (const float*)d_in[0];
  const float* w_qk = (const float*)d_in[1];
  const float* b_qk = (const float*)d_in[2];
  const float* w_v  = (const float*)d_in[3];
  const float* b_v  = (const float*)d_in[4];
  const float* w_o  = (const float*)d_in[5];
  const float* b_o  = (const float*)d_in[6];
  const float* rot  = (const float*)d_in[7];
  float* out = (float*)d_out;

  char* ws = (char*)d_ws;
  const size_t MB = 1024u * 1024u;
  float* qkf    = (float*)(ws);                 // 2 MB fp32 (hashing)
  short* qkb    = (short*)(ws + 2 * MB);        // 1 MB bf16
  short* vb     = (short*)(ws + 3 * MB);        // 1 MB bf16
  float* accumR = (float*)(ws + 4 * MB);        // 16 MB (NH*N*HD fp32)
  int* buckets  = (int*)(ws + 20 * MB);         // 256 KB
  int* perm     = (int*)(ws + 20 * MB + 256u * 1024);  // 256 KB
  int* counts   = (int*)(ws + 20 * MB + 512u * 1024);  // 128 ints
  int* cursor   = counts + 128;                         // 128 ints
  int* offsets  = cursor + 128;                         // 128 ints

  proj2_kernel<<<512, 256, 0, stream>>>(x, w_qk, b_qk, w_v, b_v,
                                        qkf, qkb, vb, counts);
  bucket_kernel<<<(NH * N) / 256, 256, 0, stream>>>(qkf, rot, buckets, counts);
  scatter_kernel<<<(NH * N) / 256, 256, 0, stream>>>(buckets, counts, cursor,
                                                     offsets, perm);
  attn_kernel<<<NH * 64, 512, 0, stream>>>(qkb, vb, perm, buckets,
                                           offsets, counts, accumR);
  outproj_kernel<<<256, 256, 0, stream>>>(accumR, w_o, b_o, out);
}

// Round 9
// 275.139 us; speedup vs baseline: 1.5532x; 1.0902x over previous
//
#include <hip/hip_runtime.h>
#include <math.h>

#define S 1024
#define DM 512
#define H 8
#define HD 64
#define NH 8          // n_hashes
#define NB 16         // n_buckets
#define N 8192        // B*H*S
#define SCALE 0.125f  // 1/sqrt(64)

typedef __attribute__((ext_vector_type(4))) float f32x4;
typedef __attribute__((ext_vector_type(8))) short s16x8;
typedef __attribute__((ext_vector_type(4))) short s16x4;

__device__ __forceinline__ short f2bf(float f) {  // RTNE float->bf16
  union { float f; unsigned u; } a; a.f = f;
  unsigned r = a.u + 0x7fffu + ((a.u >> 16) & 1u);
  return (short)(r >> 16);
}
__device__ __forceinline__ float bf2f(short h) {
  union { unsigned u; float f; } a; a.u = ((unsigned)(unsigned short)h) << 16;
  return a.f;
}
// level-l component of the 3-way bf16 split x = x0 + x1 + x2 (+eps)
__device__ __forceinline__ short lev_bf(float v, int lev) {
  short h0 = f2bf(v);
  if (lev == 0) return h0;
  float r1 = v - bf2f(h0);
  short h1 = f2bf(r1);
  if (lev == 1) return h1;
  return f2bf(r1 - bf2f(h1));
}

#if __has_builtin(__builtin_amdgcn_mfma_f32_16x16x16_bf16)
#define MFMA_PV(a, b, c) __builtin_amdgcn_mfma_f32_16x16x16_bf16(a, b, c, 0, 0, 0)
#else
#define MFMA_PV(a, b, c) __builtin_amdgcn_mfma_f32_16x16x16bf16_1k(a, b, c, 0, 0, 0)
#endif

// ---------------- K0: weight prep — Wt[lev][d][k] bf16 (transposed, split)
// wqk: 3 levels; wv, wo: 1 level. Block 0 zeroes counts+cursor.
__global__ __launch_bounds__(256) void wprep_kernel(
    const float* __restrict__ wqk, const float* __restrict__ wv,
    const float* __restrict__ wo,
    short* __restrict__ wtqk, short* __restrict__ wtv, short* __restrict__ wto,
    int* __restrict__ cz) {
  int tid = threadIdx.x;
  if (blockIdx.x == 0) cz[tid] = 0;   // counts[128] + cursor[128]
  int mat = blockIdx.x >> 6;          // 0 qk, 1 v, 2 o
  int tile = blockIdx.x & 63;
  int kt = tile >> 3, dt = tile & 7;
  const float* w = (mat == 0) ? wqk : ((mat == 1) ? wv : wo);

  __shared__ float wlds[64 * 68];
  int kr = tid >> 2, c4 = tid & 3;
  const float4* src = (const float4*)(w + (size_t)(kt * 64 + kr) * DM + dt * 64 + c4 * 16);
#pragma unroll
  for (int i = 0; i < 4; ++i) {
    float4 v = src[i];
    float* d = &wlds[kr * 68 + c4 * 16 + i * 4];
    d[0] = v.x; d[1] = v.y; d[2] = v.z; d[3] = v.w;
  }
  __syncthreads();
  int dr = tid >> 2, kc = tid & 3;
  s16x8 h0a, h0b, h1a, h1b, h2a, h2b;
#pragma unroll
  for (int i = 0; i < 8; ++i) {
    float v = wlds[(kc * 16 + i) * 68 + dr];
    short a = f2bf(v); float r1 = v - bf2f(a);
    short b = f2bf(r1); short c = f2bf(r1 - bf2f(b));
    h0a[i] = a; h1a[i] = b; h2a[i] = c;
  }
#pragma unroll
  for (int i = 0; i < 8; ++i) {
    float v = wlds[(kc * 16 + 8 + i) * 68 + dr];
    short a = f2bf(v); float r1 = v - bf2f(a);
    short b = f2bf(r1); short c = f2bf(r1 - bf2f(b));
    h0b[i] = a; h1b[i] = b; h2b[i] = c;
  }
  size_t dst = (size_t)(dt * 64 + dr) * DM + kt * 64 + kc * 16;
  if (mat == 0) {
    s16x8* p0 = (s16x8*)(wtqk + dst);
    s16x8* p1 = (s16x8*)(wtqk + (size_t)DM * DM + dst);
    s16x8* p2 = (s16x8*)(wtqk + (size_t)2 * DM * DM + dst);
    p0[0] = h0a; p0[1] = h0b; p1[0] = h1a; p1[1] = h1b; p2[0] = h2a; p2[1] = h2b;
  } else if (mat == 1) {
    s16x8* p = (s16x8*)(wtv + dst); p[0] = h0a; p[1] = h0b;
  } else {
    s16x8* p = (s16x8*)(wto + dst); p[0] = h0a; p[1] = h0b;
  }
}

// ---------------- K1: MFMA projection GEMM. nt<8: qk via bf16x3 split
// (K' = 6 x 512, products x0w0,x0w1,x1w0,x0w2,x1w1,x2w0 => fp32-accurate);
// nt>=8: v plain bf16 (K=512). Block = 64s x 64d, 4 waves each 32x32.
// Frag addressing / swizzle / C-layout copied from the verified attn kernel.
#define PST 72
__global__ __launch_bounds__(256) void projmm_kernel(
    const float* __restrict__ x, const short* __restrict__ wtqk,
    const short* __restrict__ wtv,
    const float* __restrict__ bqk, const float* __restrict__ bv,
    float* __restrict__ qkf, short* __restrict__ qkb, short* __restrict__ vb) {
  int mt = blockIdx.x & 15;
  int nt = blockIdx.x >> 4;     // 0..15
  bool isqk = nt < 8;
  int head = isqk ? nt : nt - 8;
  const short* wt = isqk ? wtqk : wtv;
  int nchunks = (isqk ? 6 : 1) * 8;

  __shared__ short a_lds[2][64 * PST];
  __shared__ short b_lds[2][64 * PST];

  int tid = threadIdx.x;
  int wave = tid >> 6, lane = tid & 63;
  int col = lane & 15, quad = lane >> 4;
  int mh = wave & 1, nh2 = wave >> 1;

  f32x4 acc[2][2];
#pragma unroll
  for (int i = 0; i < 2; ++i)
#pragma unroll
    for (int j = 0; j < 2; ++j) acc[i][j] = (f32x4){0.f, 0.f, 0.f, 0.f};

  int sr = tid >> 2, c4 = tid & 3;
  int gran = sr * PST + ((c4 ^ (sr & 3)) << 4);

  {  // stage chunk 0 (levels 0/0) into buffer 0
    const float4* xp = (const float4*)(x + (size_t)(mt * 64 + sr) * DM + c4 * 16);
    float4 f0 = xp[0], f1 = xp[1], f2 = xp[2], f3 = xp[3];
    float vv[16] = {f0.x,f0.y,f0.z,f0.w, f1.x,f1.y,f1.z,f1.w,
                    f2.x,f2.y,f2.z,f2.w, f3.x,f3.y,f3.z,f3.w};
    s16x8 ha, hb;
#pragma unroll
    for (int i = 0; i < 8; ++i) { ha[i] = f2bf(vv[i]); hb[i] = f2bf(vv[8 + i]); }
    s16x8* ad = (s16x8*)&a_lds[0][gran];
    ad[0] = ha; ad[1] = hb;
    const s16x8* wp = (const s16x8*)(wt + (size_t)(head * 64 + sr) * DM + c4 * 16);
    s16x8* bd = (s16x8*)&b_lds[0][gran];
    bd[0] = wp[0]; bd[1] = wp[1];
  }
  __syncthreads();

  for (int ci = 0; ci < nchunks; ++ci) {
    int cur = ci & 1, nxt = cur ^ 1;
    // prefetch chunk ci+1
    float4 pf0, pf1, pf2, pf3; s16x8 pw0, pw1; int pxl = 0;
    bool has = (ci + 1) < nchunks;
    if (has) {
      int kb = (ci + 1) >> 3, kc = (ci + 1) & 7;
      pxl = (0x210100 >> (kb << 2)) & 0xF;           // x level  {0,0,1,0,1,2}
      int pwl = (0x012010 >> (kb << 2)) & 0xF;       // w level  {0,1,0,2,1,0}
      const float4* xp = (const float4*)(x + (size_t)(mt * 64 + sr) * DM + kc * 64 + c4 * 16);
      pf0 = xp[0]; pf1 = xp[1]; pf2 = xp[2]; pf3 = xp[3];
      const s16x8* wp = (const s16x8*)(wt + (size_t)pwl * DM * DM +
                                       (size_t)(head * 64 + sr) * DM + kc * 64 + c4 * 16);
      pw0 = wp[0]; pw1 = wp[1];
    }
    // compute chunk ci from buffer cur
#pragma unroll
    for (int s2 = 0; s2 < 2; ++s2) {
      s16x8 af[2], bfv[2];
#pragma unroll
      for (int mi = 0; mi < 2; ++mi) {
        int row = mh * 32 + mi * 16 + col;
        int cidx = ((s2 << 1) + (quad >> 1)) ^ (row & 3);
        af[mi] = *(const s16x8*)&a_lds[cur][row * PST + (cidx << 4) + ((quad & 1) << 3)];
      }
#pragma unroll
      for (int ni = 0; ni < 2; ++ni) {
        int row = nh2 * 32 + ni * 16 + col;
        int cidx = ((s2 << 1) + (quad >> 1)) ^ (row & 3);
        bfv[ni] = *(const s16x8*)&b_lds[cur][row * PST + (cidx << 4) + ((quad & 1) << 3)];
      }
#pragma unroll
      for (int mi = 0; mi < 2; ++mi)
#pragma unroll
        for (int ni = 0; ni < 2; ++ni)
          acc[mi][ni] = __builtin_amdgcn_mfma_f32_16x16x32_bf16(af[mi], bfv[ni],
                                                               acc[mi][ni], 0, 0, 0);
    }
    // write prefetched chunk
    if (has) {
      float vv[16] = {pf0.x,pf0.y,pf0.z,pf0.w, pf1.x,pf1.y,pf1.z,pf1.w,
                      pf2.x,pf2.y,pf2.z,pf2.w, pf3.x,pf3.y,pf3.z,pf3.w};
      s16x8 ha, hb;
#pragma unroll
      for (int i = 0; i < 8; ++i) { ha[i] = lev_bf(vv[i], pxl); hb[i] = lev_bf(vv[8 + i], pxl); }
      s16x8* ad = (s16x8*)&a_lds[nxt][gran];
      ad[0] = ha; ad[1] = hb;
      s16x8* bd = (s16x8*)&b_lds[nxt][gran];
      bd[0] = pw0; bd[1] = pw1;
    }
    __syncthreads();
  }
  // epilogue: C col=lane&15 -> d, row=quad*4+u -> s  (attn-verified mapping)
  const float* bias = isqk ? bqk : bv;
#pragma unroll
  for (int ni = 0; ni < 2; ++ni) {
    int nl = nh2 * 32 + ni * 16 + col;
    float bb = bias[head * 64 + nl];
#pragma unroll
    for (int mi = 0; mi < 2; ++mi) {
#pragma unroll
      for (int u = 0; u < 4; ++u) {
        int s = mt * 64 + mh * 32 + mi * 16 + quad * 4 + u;
        float val = acc[mi][ni][u] + bb;
        size_t idx = ((size_t)head * S + s) * HD + nl;
        if (isqk) { qkf[idx] = val; qkb[idx] = f2bf(val); }
        else vb[idx] = f2bf(val);
      }
    }
  }
}

// ---------------- K2: LSH buckets + ballot-aggregated histogram (verbatim r8)
__global__ void bucket_kernel(const float* __restrict__ qkf,
                              const float* __restrict__ rot,
                              int* __restrict__ buckets,
                              int* __restrict__ counts) {
  int g = blockIdx.x * blockDim.x + threadIdx.x;
  int n = g & (N - 1);
  int r = g >> 13;
  int h = n >> 10;
  int lane = threadIdx.x & 63;
  const float4* q4 = (const float4*)(qkf + (size_t)n * HD);
  const float* R = rot + (size_t)((r * H + h) * HD) * 8;
  float v[8];
#pragma unroll
  for (int c = 0; c < 8; ++c) v[c] = 0.f;
  for (int d4 = 0; d4 < 16; ++d4) {
    float4 q = q4[d4];
    const float* Rr = R + d4 * 32;
#pragma unroll
    for (int c = 0; c < 8; ++c) v[c] = fmaf(q.x, Rr[c], v[c]);
#pragma unroll
    for (int c = 0; c < 8; ++c) v[c] = fmaf(q.y, Rr[8 + c], v[c]);
#pragma unroll
    for (int c = 0; c < 8; ++c) v[c] = fmaf(q.z, Rr[16 + c], v[c]);
#pragma unroll
    for (int c = 0; c < 8; ++c) v[c] = fmaf(q.w, Rr[24 + c], v[c]);
  }
  float best = v[0];
  int bi = 0;
#pragma unroll
  for (int c = 1; c < 16; ++c) {
    float val = (c < 8) ? v[c] : -v[c - 8];
    if (val > best) { best = val; bi = c; }
  }
  buckets[r * N + n] = bi;
  for (int bk = 0; bk < NB; ++bk) {
    unsigned long long mask = __ballot(bi == bk);
    if (mask && lane == (__ffsll((long long)mask) - 1))
      atomicAdd(&counts[r * NB + bk], __popcll(mask));
  }
}

// ---------------- K3: scatter with fused scan (verbatim r8)
__global__ __launch_bounds__(256) void scatter_kernel(
    const int* __restrict__ buckets, const int* __restrict__ counts,
    int* __restrict__ cursor, int* __restrict__ offsets,
    int* __restrict__ perm) {
  __shared__ int cnt_s[128];
  __shared__ int off_s[128];
  int tid = threadIdx.x;
  if (tid < 128) cnt_s[tid] = counts[tid];
  __syncthreads();
  if (tid < 128) {
    int r = tid >> 4, b = tid & 15;
    int off = r * N;
    for (int i = 0; i < b; ++i) off += cnt_s[(r << 4) + i];
    off_s[tid] = off;
    if (blockIdx.x == 0) offsets[tid] = off;
  }
  __syncthreads();
  int g = blockIdx.x * 256 + tid;
  int n = g & (N - 1);
  int r = g >> 13;
  int lane = tid & 63;
  int b = buckets[r * N + n];
  for (int bk = 0; bk < NB; ++bk) {
    unsigned long long mask = __ballot(b == bk);
    if (!mask) continue;
    int leader = __ffsll((long long)mask) - 1;
    int base = 0;
    if (lane == leader) base = atomicAdd(&cursor[(r << 4) + bk], __popcll(mask));
    base = __shfl(base, leader);
    if (b == bk) {
      int rank = __popcll(mask & ((1ull << lane) - 1ull));
      perm[off_s[(r << 4) + bk] + base + rank] = n;
    }
  }
}

// ---------------- K4: MFMA attention (verbatim r8)
#define KT 64
#define KST 72
#define VST 72
__global__ __launch_bounds__(512) void attn_kernel(
    const short* __restrict__ qkb, const short* __restrict__ vb,
    const int* __restrict__ perm, const int* __restrict__ buckets,
    const int* __restrict__ offsets, const int* __restrict__ counts,
    float* __restrict__ accumR) {
  int r = blockIdx.x >> 6;
  int pb = blockIdx.x & 63;
  int tid = threadIdx.x;
  int wave = tid >> 6, lane = tid & 63;
  int col = lane & 15, quad = lane >> 4;

  __shared__ short k_lds[2][KT * KST];
  __shared__ short v_lds[2][KT * VST];
  __shared__ int sse[2];

  int p = r * N + (pb << 7) + (wave << 4) + col;
  int qidx = perm[p];
  int qb = buckets[r * N + qidx];
  int q_start = offsets[r * NB + qb];
  int q_end = q_start + counts[r * NB + qb];

  if (tid == 0) sse[0] = q_start;
  if (tid == 511) sse[1] = q_end;
  for (int e = tid; e < KT * VST; e += 512) ((int*)v_lds)[e] = 0;

  s16x8 qa[2];
#pragma unroll
  for (int s2 = 0; s2 < 2; ++s2)
    qa[s2] = *(const s16x8*)(qkb + (size_t)qidx * HD + s2 * 32 + quad * 8);

  int wbs = __shfl(q_start, 0);
  int wbe = __shfl(q_end, 15);
  __syncthreads();
  int bs = sse[0], be = sse[1];

  float lsum = 0.f;
  f32x4 o0 = {0,0,0,0}, o1 = {0,0,0,0}, o2 = {0,0,0,0}, o3 = {0,0,0,0};

  int jsk = tid >> 2, csk = tid & 3;
  bool stager = tid < 256;
  int kgran = jsk * KST + ((csk ^ (jsk & 3)) << 4);
  int vgran = jsk * VST + (csk << 4);

  {
    int nj = min(KT, be - bs);
    if (stager && jsk < nj) {
      int g = perm[bs + jsk];
      const s16x8* kp = (const s16x8*)(qkb + (size_t)g * HD + (csk << 4));
      const s16x8* vp = (const s16x8*)(vb + (size_t)g * HD + (csk << 4));
      s16x8 a0 = kp[0], a1 = kp[1], b0 = vp[0], b1 = vp[1];
      s16x8* kd = (s16x8*)&k_lds[0][kgran];
      kd[0] = a0; kd[1] = a1;
      s16x8* vd = (s16x8*)&v_lds[0][vgran];
      vd[0] = b0; vd[1] = b1;
    }
  }
  __syncthreads();

  int ntiles = (be - bs + KT - 1) >> 6;
  for (int t = 0; t < ntiles; ++t) {
    int jt = bs + (t << 6);
    int cur = t & 1, nxt = cur ^ 1;
    s16x8 a0, a1, b0, b1;
    bool pf_ok = false;
    int jn = jt + KT;
    if (jn < be && stager) {
      int njn = min(KT, be - jn);
      if (jsk < njn) {
        pf_ok = true;
        int g = perm[jn + jsk];
        const s16x8* kp = (const s16x8*)(qkb + (size_t)g * HD + (csk << 4));
        const s16x8* vp = (const s16x8*)(vb + (size_t)g * HD + (csk << 4));
        a0 = kp[0]; a1 = kp[1]; b0 = vp[0]; b1 = vp[1];
      }
    }
    if (jt < wbe && jt + KT > wbs) {
      int c_lo = (wbs > jt) ? ((wbs - jt) >> 4) : 0;
      int c_hi = min(4, (wbe - jt + 15) >> 4);
      for (int c16 = c_lo; c16 < c_hi; ++c16) {
        f32x4 sacc = {0,0,0,0};
        int key = (c16 << 4) + col;
        const short* kb = &k_lds[cur][key * KST];
#pragma unroll
        for (int s2 = 0; s2 < 2; ++s2) {
          int cidx = ((s2 << 1) + (quad >> 1)) ^ (key & 3);
          s16x8 kf = *(const s16x8*)&kb[(cidx << 4) + ((quad & 1) << 3)];
          sacc = __builtin_amdgcn_mfma_f32_16x16x32_bf16(kf, qa[s2], sacc, 0, 0, 0);
        }
        int kbase = jt + (c16 << 4) + (quad << 2);
        float pw[4];
#pragma unroll
        for (int u = 0; u < 4; ++u) {
          int pos = kbase + u;
          bool ok = (pos >= q_start) && (pos < q_end);
          pw[u] = ok ? __expf(sacc[u] * SCALE) : 0.f;
        }
        lsum += (pw[0] + pw[1]) + (pw[2] + pw[3]);
        s16x4 pfr;
        pfr[0] = f2bf(pw[0]); pfr[1] = f2bf(pw[1]);
        pfr[2] = f2bf(pw[2]); pfr[3] = f2bf(pw[3]);
        const short* vbp = &v_lds[cur][((c16 << 4) + (quad << 2)) * VST + col];
#pragma unroll
        for (int c = 0; c < 4; ++c) {
          s16x4 vfr;
#pragma unroll
          for (int j = 0; j < 4; ++j)
            vfr[j] = vbp[j * VST + (c << 4)];
          if (c == 0) o0 = MFMA_PV(pfr, vfr, o0);
          else if (c == 1) o1 = MFMA_PV(pfr, vfr, o1);
          else if (c == 2) o2 = MFMA_PV(pfr, vfr, o2);
          else o3 = MFMA_PV(pfr, vfr, o3);
        }
      }
    }
    if (pf_ok) {
      s16x8* kd = (s16x8*)&k_lds[nxt][kgran];
      kd[0] = a0; kd[1] = a1;
      s16x8* vd = (s16x8*)&v_lds[nxt][vgran];
      vd[0] = b0; vd[1] = b1;
    }
    __syncthreads();
  }

  lsum += __shfl_xor(lsum, 16);
  lsum += __shfl_xor(lsum, 32);
  float inv = 1.f / lsum;
#pragma unroll
  for (int u = 0; u < 4; ++u) {
    int slot = (quad << 2) + u;
    float inv_u = __shfl(inv, slot);
    int qidx_u = __shfl(qidx, slot);
    float* dst = accumR + ((size_t)r * N + qidx_u) * HD + col;
    dst[0]  = o0[u] * inv_u;
    dst[16] = o1[u] * inv_u;
    dst[32] = o2[u] * inv_u;
    dst[48] = o3[u] * inv_u;
  }
}

// ---------------- K5: MFMA output projection. Block = 32s x 64d, 4 waves
// each 16x32. A = (sum_r accumR)/8 -> bf16 staged in-kernel; B = wto prepped.
__global__ __launch_bounds__(256) void outproj_kernel(
    const float* __restrict__ accumR, const short* __restrict__ wto,
    const float* __restrict__ bo, float* __restrict__ out) {
  int mt = blockIdx.x & 31;   // s-tile of 32
  int nt = blockIdx.x >> 5;   // d-tile of 64
  __shared__ short a_lds[2][32 * PST];
  __shared__ short b_lds[2][64 * PST];
  int tid = threadIdx.x;
  int wave = tid >> 6, lane = tid & 63;
  int col = lane & 15, quad = lane >> 4;
  int mi2 = wave & 1, nh2 = wave >> 1;

  f32x4 acc[2];
  acc[0] = (f32x4){0.f,0.f,0.f,0.f};
  acc[1] = (f32x4){0.f,0.f,0.f,0.f};

  bool isA = tid < 128;
  int sr = tid >> 2, c4 = tid & 3;                 // A stager (t<128): row 0..31
  int agran = sr * PST + ((c4 ^ (sr & 3)) << 4);
  int dl = (tid - 128) >> 1, gp = tid & 1;         // B stager: row 0..63, gran-pair

  {  // stage chunk 0
    if (isA) {
      size_t abase = ((size_t)0 * S + mt * 32 + sr) * HD + c4 * 16;
      f32x4 s0 = {0,0,0,0}, s1 = {0,0,0,0}, s2v = {0,0,0,0}, s3v = {0,0,0,0};
#pragma unroll
      for (int r = 0; r < NH; ++r) {
        const f32x4* ap = (const f32x4*)(accumR + (size_t)r * N * HD + abase);
        s0 += ap[0]; s1 += ap[1]; s2v += ap[2]; s3v += ap[3];
      }
      s16x8 ha, hb;
#pragma unroll
      for (int i = 0; i < 4; ++i) {
        ha[i] = f2bf(s0[i] * 0.125f); ha[4 + i] = f2bf(s1[i] * 0.125f);
        hb[i] = f2bf(s2v[i] * 0.125f); hb[4 + i] = f2bf(s3v[i] * 0.125f);
      }
      s16x8* ad = (s16x8*)&a_lds[0][agran];
      ad[0] = ha; ad[1] = hb;
    } else {
      const s16x8* wp = (const s16x8*)(wto + (size_t)(nt * 64 + dl) * DM + gp * 32);
      int g0 = gp * 2;
      s16x8* d0 = (s16x8*)&b_lds[0][dl * PST + ((g0 ^ (dl & 3)) << 4)];
      d0[0] = wp[0]; d0[1] = wp[1];
      s16x8* d1 = (s16x8*)&b_lds[0][dl * PST + (((g0 + 1) ^ (dl & 3)) << 4)];
      d1[0] = wp[2]; d1[1] = wp[3];
    }
  }
  __syncthreads();

  for (int kc = 0; kc < 8; ++kc) {
    int cur = kc & 1, nxt = cur ^ 1;
    bool has = kc + 1 < 8;
    f32x4 s0 = {0,0,0,0}, s1 = {0,0,0,0}, s2v = {0,0,0,0}, s3v = {0,0,0,0};
    s16x8 pb0, pb1, pb2, pb3;
    if (has) {
      if (isA) {
        size_t abase = ((size_t)(kc + 1) * S + mt * 32 + sr) * HD + c4 * 16;
#pragma unroll
        for (int r = 0; r < NH; ++r) {
          const f32x4* ap = (const f32x4*)(accumR + (size_t)r * N * HD + abase);
          s0 += ap[0]; s1 += ap[1]; s2v += ap[2]; s3v += ap[3];
        }
      } else {
        const s16x8* wp = (const s16x8*)(wto + (size_t)(nt * 64 + dl) * DM +
                                         (kc + 1) * 64 + gp * 32);
        pb0 = wp[0]; pb1 = wp[1]; pb2 = wp[2]; pb3 = wp[3];
      }
    }
    // compute chunk kc
#pragma unroll
    for (int s2 = 0; s2 < 2; ++s2) {
      int arow = mi2 * 16 + col;
      int acidx = ((s2 << 1) + (quad >> 1)) ^ (arow & 3);
      s16x8 af = *(const s16x8*)&a_lds[cur][arow * PST + (acidx << 4) + ((quad & 1) << 3)];
      s16x8 bfv[2];
#pragma unroll
      for (int ni = 0; ni < 2; ++ni) {
        int brow = nh2 * 32 + ni * 16 + col;
        int bcidx = ((s2 << 1) + (quad >> 1)) ^ (brow & 3);
        bfv[ni] = *(const s16x8*)&b_lds[cur][brow * PST + (bcidx << 4) + ((quad & 1) << 3)];
      }
#pragma unroll
      for (int ni = 0; ni < 2; ++ni)
        acc[ni] = __builtin_amdgcn_mfma_f32_16x16x32_bf16(af, bfv[ni], acc[ni], 0, 0, 0);
    }
    if (has) {
      if (isA) {
        s16x8 ha, hb;
#pragma unroll
        for (int i = 0; i < 4; ++i) {
          ha[i] = f2bf(s0[i] * 0.125f); ha[4 + i] = f2bf(s1[i] * 0.125f);
          hb[i] = f2bf(s2v[i] * 0.125f); hb[4 + i] = f2bf(s3v[i] * 0.125f);
        }
        s16x8* ad = (s16x8*)&a_lds[nxt][agran];
        ad[0] = ha; ad[1] = hb;
      } else {
        int g0 = gp * 2;
        s16x8* d0 = (s16x8*)&b_lds[nxt][dl * PST + ((g0 ^ (dl & 3)) << 4)];
        d0[0] = pb0; d0[1] = pb1;
        s16x8* d1 = (s16x8*)&b_lds[nxt][dl * PST + (((g0 + 1) ^ (dl & 3)) << 4)];
        d1[0] = pb2; d1[1] = pb3;
      }
    }
    __syncthreads();
  }
  // epilogue
#pragma unroll
  for (int ni = 0; ni < 2; ++ni) {
    int nl = nh2 * 32 + ni * 16 + col;
    int dgl = nt * 64 + nl;
    float bb = bo[dgl];
#pragma unroll
    for (int u = 0; u < 4; ++u) {
      int s = mt * 32 + mi2 * 16 + quad * 4 + u;
      out[(size_t)s * DM + dgl] = acc[ni][u] + bb;
    }
  }
}

extern "C" void kernel_launch(void* const* d_in, const int* in_sizes, int n_in,
                              void* d_out, int out_size, void* d_ws, size_t ws_size,
                              hipStream_t stream) {
  const float* x    = (const float*)d_in[0];
  const float* w_qk = (const float*)d_in[1];
  const float* b_qk = (const float*)d_in[2];
  const float* w_v  = (const float*)d_in[3];
  const float* b_v  = (const float*)d_in[4];
  const float* w_o  = (const float*)d_in[5];
  const float* b_o  = (const float*)d_in[6];
  const float* rot  = (const float*)d_in[7];
  float* out = (float*)d_out;

  char* ws = (char*)d_ws;
  const size_t MB = 1024u * 1024u;
  float* qkf    = (float*)(ws);                       // 2 MB fp32 (hashing)
  short* qkb    = (short*)(ws + 2 * MB);              // 1 MB bf16
  short* vb     = (short*)(ws + 3 * MB);              // 1 MB bf16
  float* accumR = (float*)(ws + 4 * MB);              // 16 MB
  short* wtqk   = (short*)(ws + 20 * MB);             // 1.5 MB (3 levels)
  short* wtv    = (short*)(ws + 20 * MB + 1536u * 1024);  // 0.5 MB
  short* wto    = (short*)(ws + 22 * MB);             // 0.5 MB
  int* buckets  = (int*)(ws + 22 * MB + 512u * 1024); // 256 KB
  int* perm     = (int*)(ws + 22 * MB + 768u * 1024); // 256 KB
  int* counts   = (int*)(ws + 23 * MB);               // 128 ints
  int* cursor   = counts + 128;                       // 128 ints
  int* offsets  = cursor + 128;                       // 128 ints

  wprep_kernel<<<192, 256, 0, stream>>>(w_qk, w_v, w_o, wtqk, wtv, wto, counts);
  projmm_kernel<<<256, 256, 0, stream>>>(x, wtqk, wtv, b_qk, b_v, qkf, qkb, vb);
  bucket_kernel<<<(NH * N) / 256, 256, 0, stream>>>(qkf, rot, buckets, counts);
  scatter_kernel<<<(NH * N) / 256, 256, 0, stream>>>(buckets, counts, cursor,
                                                     offsets, perm);
  attn_kernel<<<NH * 64, 512, 0, stream>>>(qkb, vb, perm, buckets,
                                           offsets, counts, accumR);
  outproj_kernel<<<256, 256, 0, stream>>>(accumR, wto, b_o, out);
}

// Round 10
// 265.379 us; speedup vs baseline: 1.6103x; 1.0368x over previous
//
#include <hip/hip_runtime.h>
#include <math.h>

#define S 1024
#define DM 512
#define H 8
#define HD 64
#define NH 8          // n_hashes
#define NB 16         // n_buckets
#define N 8192        // B*H*S
#define SCALE 0.125f  // 1/sqrt(64)

typedef __attribute__((ext_vector_type(4))) float f32x4;
typedef __attribute__((ext_vector_type(8))) short s16x8;
typedef __attribute__((ext_vector_type(4))) short s16x4;

__device__ __forceinline__ short f2bf(float f) {  // RTNE float->bf16
  union { float f; unsigned u; } a; a.f = f;
  unsigned r = a.u + 0x7fffu + ((a.u >> 16) & 1u);
  return (short)(r >> 16);
}
__device__ __forceinline__ float bf2f(short h) {
  union { unsigned u; float f; } a; a.u = ((unsigned)(unsigned short)h) << 16;
  return a.f;
}
__device__ __forceinline__ int f2bf2(float lo, float hi) {
  return (int)(unsigned short)f2bf(lo) | (((int)f2bf(hi)) << 16);
}
// level-l component of the 3-way bf16 split x = x0 + x1 + x2 (+eps)
__device__ __forceinline__ short lev_bf(float v, int lev) {
  short h0 = f2bf(v);
  if (lev == 0) return h0;
  float r1 = v - bf2f(h0);
  short h1 = f2bf(r1);
  if (lev == 1) return h1;
  return f2bf(r1 - bf2f(h1));
}

#if __has_builtin(__builtin_amdgcn_mfma_f32_16x16x16_bf16)
#define MFMA_PV(a, b, c) __builtin_amdgcn_mfma_f32_16x16x16_bf16(a, b, c, 0, 0, 0)
#else
#define MFMA_PV(a, b, c) __builtin_amdgcn_mfma_f32_16x16x16bf16_1k(a, b, c, 0, 0, 0)
#endif

// ---------------- K0: weight prep — Wt[lev][d][k] bf16 (transposed, split)
// wqk: 3 levels; wv, wo: 1 level. Block 0 zeroes counts+cursor.
__global__ __launch_bounds__(256) void wprep_kernel(
    const float* __restrict__ wqk, const float* __restrict__ wv,
    const float* __restrict__ wo,
    short* __restrict__ wtqk, short* __restrict__ wtv, short* __restrict__ wto,
    int* __restrict__ cz) {
  int tid = threadIdx.x;
  if (blockIdx.x == 0) cz[tid] = 0;   // counts[128] + cursor[128]
  int mat = blockIdx.x >> 6;          // 0 qk, 1 v, 2 o
  int tile = blockIdx.x & 63;
  int kt = tile >> 3, dt = tile & 7;
  const float* w = (mat == 0) ? wqk : ((mat == 1) ? wv : wo);

  __shared__ float wlds[64 * 68];
  int kr = tid >> 2, c4 = tid & 3;
  const float4* src = (const float4*)(w + (size_t)(kt * 64 + kr) * DM + dt * 64 + c4 * 16);
#pragma unroll
  for (int i = 0; i < 4; ++i) {
    float4 v = src[i];
    float* d = &wlds[kr * 68 + c4 * 16 + i * 4];
    d[0] = v.x; d[1] = v.y; d[2] = v.z; d[3] = v.w;
  }
  __syncthreads();
  int dr = tid >> 2, kc = tid & 3;
  s16x8 h0a, h0b, h1a, h1b, h2a, h2b;
#pragma unroll
  for (int i = 0; i < 8; ++i) {
    float v = wlds[(kc * 16 + i) * 68 + dr];
    short a = f2bf(v); float r1 = v - bf2f(a);
    short b = f2bf(r1); short c = f2bf(r1 - bf2f(b));
    h0a[i] = a; h1a[i] = b; h2a[i] = c;
  }
#pragma unroll
  for (int i = 0; i < 8; ++i) {
    float v = wlds[(kc * 16 + 8 + i) * 68 + dr];
    short a = f2bf(v); float r1 = v - bf2f(a);
    short b = f2bf(r1); short c = f2bf(r1 - bf2f(b));
    h0b[i] = a; h1b[i] = b; h2b[i] = c;
  }
  size_t dst = (size_t)(dt * 64 + dr) * DM + kt * 64 + kc * 16;
  if (mat == 0) {
    s16x8* p0 = (s16x8*)(wtqk + dst);
    s16x8* p1 = (s16x8*)(wtqk + (size_t)DM * DM + dst);
    s16x8* p2 = (s16x8*)(wtqk + (size_t)2 * DM * DM + dst);
    p0[0] = h0a; p0[1] = h0b; p1[0] = h1a; p1[1] = h1b; p2[0] = h2a; p2[1] = h2b;
  } else if (mat == 1) {
    s16x8* p = (s16x8*)(wtv + dst); p[0] = h0a; p[1] = h0b;
  } else {
    s16x8* p = (s16x8*)(wto + dst); p[0] = h0a; p[1] = h0b;
  }
}

// ---------------- K1: MFMA projection GEMM, split-K balanced.
// Grid 896 = 16 mt x (6 qk-splits + 1 v) x 8 heads; EVERY block runs exactly
// 8 K-chunks. qk split sp computes x_{xl} @ w_{wl} (bf16x3 6-product pairs,
// fp32-accurate sum) into its own fp32 slab qkpart[sp]; v writes bf16 vb.
#define PST 72
__global__ __launch_bounds__(256) void projmm_kernel(
    const float* __restrict__ x, const short* __restrict__ wtqk,
    const short* __restrict__ wtv,
    const float* __restrict__ bqk, const float* __restrict__ bv,
    float* __restrict__ qkpart, short* __restrict__ vb) {
  int mt = blockIdx.x & 15;
  int rest = blockIdx.x >> 4;   // 0..55
  int sp = rest >> 3;           // 0..5 qk split, 6 = v
  int head = rest & 7;
  bool isv = (sp == 6);
  int xl = isv ? 0 : ((0x210100 >> (sp << 2)) & 0xF);  // {0,0,1,0,1,2}
  int wl = isv ? 0 : ((0x012010 >> (sp << 2)) & 0xF);  // {0,1,0,2,1,0}
  const short* wt = isv ? wtv : (wtqk + (size_t)wl * DM * DM);

  __shared__ short a_lds[2][64 * PST];
  __shared__ short b_lds[2][64 * PST];

  int tid = threadIdx.x;
  int wave = tid >> 6, lane = tid & 63;
  int col = lane & 15, quad = lane >> 4;
  int mh = wave & 1, nh2 = wave >> 1;

  f32x4 acc[2][2];
#pragma unroll
  for (int i = 0; i < 2; ++i)
#pragma unroll
    for (int j = 0; j < 2; ++j) acc[i][j] = (f32x4){0.f, 0.f, 0.f, 0.f};

  int sr = tid >> 2, c4 = tid & 3;
  int gran = sr * PST + ((c4 ^ (sr & 3)) << 4);

  {  // stage chunk 0 into buffer 0
    const float4* xp = (const float4*)(x + (size_t)(mt * 64 + sr) * DM + c4 * 16);
    float4 f0 = xp[0], f1 = xp[1], f2 = xp[2], f3 = xp[3];
    float vv[16] = {f0.x,f0.y,f0.z,f0.w, f1.x,f1.y,f1.z,f1.w,
                    f2.x,f2.y,f2.z,f2.w, f3.x,f3.y,f3.z,f3.w};
    s16x8 ha, hb;
#pragma unroll
    for (int i = 0; i < 8; ++i) { ha[i] = lev_bf(vv[i], xl); hb[i] = lev_bf(vv[8 + i], xl); }
    s16x8* ad = (s16x8*)&a_lds[0][gran];
    ad[0] = ha; ad[1] = hb;
    const s16x8* wp = (const s16x8*)(wt + (size_t)(head * 64 + sr) * DM + c4 * 16);
    s16x8* bd = (s16x8*)&b_lds[0][gran];
    bd[0] = wp[0]; bd[1] = wp[1];
  }
  __syncthreads();

  for (int ci = 0; ci < 8; ++ci) {
    int cur = ci & 1, nxt = cur ^ 1;
    float4 pf0, pf1, pf2, pf3; s16x8 pw0, pw1;
    bool has = (ci + 1) < 8;
    if (has) {
      int kc = ci + 1;
      const float4* xp = (const float4*)(x + (size_t)(mt * 64 + sr) * DM + kc * 64 + c4 * 16);
      pf0 = xp[0]; pf1 = xp[1]; pf2 = xp[2]; pf3 = xp[3];
      const s16x8* wp = (const s16x8*)(wt + (size_t)(head * 64 + sr) * DM + kc * 64 + c4 * 16);
      pw0 = wp[0]; pw1 = wp[1];
    }
    // compute chunk ci from buffer cur
#pragma unroll
    for (int s2 = 0; s2 < 2; ++s2) {
      s16x8 af[2], bfv[2];
#pragma unroll
      for (int mi = 0; mi < 2; ++mi) {
        int row = mh * 32 + mi * 16 + col;
        int cidx = ((s2 << 1) + (quad >> 1)) ^ (row & 3);
        af[mi] = *(const s16x8*)&a_lds[cur][row * PST + (cidx << 4) + ((quad & 1) << 3)];
      }
#pragma unroll
      for (int ni = 0; ni < 2; ++ni) {
        int row = nh2 * 32 + ni * 16 + col;
        int cidx = ((s2 << 1) + (quad >> 1)) ^ (row & 3);
        bfv[ni] = *(const s16x8*)&b_lds[cur][row * PST + (cidx << 4) + ((quad & 1) << 3)];
      }
#pragma unroll
      for (int mi = 0; mi < 2; ++mi)
#pragma unroll
        for (int ni = 0; ni < 2; ++ni)
          acc[mi][ni] = __builtin_amdgcn_mfma_f32_16x16x32_bf16(af[mi], bfv[ni],
                                                               acc[mi][ni], 0, 0, 0);
    }
    if (has) {
      float vv[16] = {pf0.x,pf0.y,pf0.z,pf0.w, pf1.x,pf1.y,pf1.z,pf1.w,
                      pf2.x,pf2.y,pf2.z,pf2.w, pf3.x,pf3.y,pf3.z,pf3.w};
      s16x8 ha, hb;
#pragma unroll
      for (int i = 0; i < 8; ++i) { ha[i] = lev_bf(vv[i], xl); hb[i] = lev_bf(vv[8 + i], xl); }
      s16x8* ad = (s16x8*)&a_lds[nxt][gran];
      ad[0] = ha; ad[1] = hb;
      s16x8* bd = (s16x8*)&b_lds[nxt][gran];
      bd[0] = pw0; bd[1] = pw1;
    }
    __syncthreads();
  }
  // epilogue: C col=lane&15 -> d, row=quad*4+u -> s  (attn-verified mapping)
  if (isv) {
#pragma unroll
    for (int ni = 0; ni < 2; ++ni) {
      int nl = nh2 * 32 + ni * 16 + col;
      float bb = bv[head * 64 + nl];
#pragma unroll
      for (int mi = 0; mi < 2; ++mi)
#pragma unroll
        for (int u = 0; u < 4; ++u) {
          int s = mt * 64 + mh * 32 + mi * 16 + quad * 4 + u;
          vb[((size_t)head * S + s) * HD + nl] = f2bf(acc[mi][ni][u] + bb);
        }
    }
  } else {
    float* dst = qkpart + (size_t)sp * N * HD;
#pragma unroll
    for (int ni = 0; ni < 2; ++ni) {
      int nl = nh2 * 32 + ni * 16 + col;
      float bb = (sp == 0) ? bqk[head * 64 + nl] : 0.f;
#pragma unroll
      for (int mi = 0; mi < 2; ++mi)
#pragma unroll
        for (int u = 0; u < 4; ++u) {
          int s = mt * 64 + mh * 32 + mi * 16 + quad * 4 + u;
          dst[((size_t)head * S + s) * HD + nl] = acc[mi][ni][u] + bb;
        }
    }
  }
}

// ---------------- K2: LSH buckets: sums the 6 fp32 slabs (deterministic),
// hashes, histograms; r==0 threads also emit the bf16 qkb for attention.
__global__ void bucket_kernel(const float* __restrict__ qkpart,
                              const float* __restrict__ rot,
                              int* __restrict__ buckets,
                              int* __restrict__ counts,
                              short* __restrict__ qkb) {
  int g = blockIdx.x * blockDim.x + threadIdx.x;
  int n = g & (N - 1);
  int r = g >> 13;
  int h = n >> 10;
  int lane = threadIdx.x & 63;
  const float* R = rot + (size_t)((r * H + h) * HD) * 8;
  float v[8];
#pragma unroll
  for (int c = 0; c < 8; ++c) v[c] = 0.f;
  for (int d4 = 0; d4 < 16; ++d4) {
    f32x4 q = ((const f32x4*)(qkpart + (size_t)n * HD))[d4];
#pragma unroll
    for (int sl = 1; sl < 6; ++sl)
      q += ((const f32x4*)(qkpart + (size_t)sl * N * HD + (size_t)n * HD))[d4];
    if (r == 0) {
      int2 pk = make_int2(f2bf2(q[0], q[1]), f2bf2(q[2], q[3]));
      *(int2*)(qkb + (size_t)n * HD + d4 * 4) = pk;
    }
    const float* Rr = R + d4 * 32;
#pragma unroll
    for (int c = 0; c < 8; ++c) v[c] = fmaf(q[0], Rr[c], v[c]);
#pragma unroll
    for (int c = 0; c < 8; ++c) v[c] = fmaf(q[1], Rr[8 + c], v[c]);
#pragma unroll
    for (int c = 0; c < 8; ++c) v[c] = fmaf(q[2], Rr[16 + c], v[c]);
#pragma unroll
    for (int c = 0; c < 8; ++c) v[c] = fmaf(q[3], Rr[24 + c], v[c]);
  }
  float best = v[0];
  int bi = 0;
#pragma unroll
  for (int c = 1; c < 16; ++c) {
    float val = (c < 8) ? v[c] : -v[c - 8];
    if (val > best) { best = val; bi = c; }
  }
  buckets[r * N + n] = bi;
  for (int bk = 0; bk < NB; ++bk) {
    unsigned long long mask = __ballot(bi == bk);
    if (mask && lane == (__ffsll((long long)mask) - 1))
      atomicAdd(&counts[r * NB + bk], __popcll(mask));
  }
}

// ---------------- K3: scatter with fused scan (verbatim)
__global__ __launch_bounds__(256) void scatter_kernel(
    const int* __restrict__ buckets, const int* __restrict__ counts,
    int* __restrict__ cursor, int* __restrict__ offsets,
    int* __restrict__ perm) {
  __shared__ int cnt_s[128];
  __shared__ int off_s[128];
  int tid = threadIdx.x;
  if (tid < 128) cnt_s[tid] = counts[tid];
  __syncthreads();
  if (tid < 128) {
    int r = tid >> 4, b = tid & 15;
    int off = r * N;
    for (int i = 0; i < b; ++i) off += cnt_s[(r << 4) + i];
    off_s[tid] = off;
    if (blockIdx.x == 0) offsets[tid] = off;
  }
  __syncthreads();
  int g = blockIdx.x * 256 + tid;
  int n = g & (N - 1);
  int r = g >> 13;
  int lane = tid & 63;
  int b = buckets[r * N + n];
  for (int bk = 0; bk < NB; ++bk) {
    unsigned long long mask = __ballot(b == bk);
    if (!mask) continue;
    int leader = __ffsll((long long)mask) - 1;
    int base = 0;
    if (lane == leader) base = atomicAdd(&cursor[(r << 4) + bk], __popcll(mask));
    base = __shfl(base, leader);
    if (b == bk) {
      int rank = __popcll(mask & ((1ull << lane) - 1ull));
      perm[off_s[(r << 4) + bk] + base + rank] = n;
    }
  }
}

// ---------------- K4: MFMA attention (verbatim r8)
#define KT 64
#define KST 72
#define VST 72
__global__ __launch_bounds__(512) void attn_kernel(
    const short* __restrict__ qkb, const short* __restrict__ vb,
    const int* __restrict__ perm, const int* __restrict__ buckets,
    const int* __restrict__ offsets, const int* __restrict__ counts,
    float* __restrict__ accumR) {
  int r = blockIdx.x >> 6;
  int pb = blockIdx.x & 63;
  int tid = threadIdx.x;
  int wave = tid >> 6, lane = tid & 63;
  int col = lane & 15, quad = lane >> 4;

  __shared__ short k_lds[2][KT * KST];
  __shared__ short v_lds[2][KT * VST];
  __shared__ int sse[2];

  int p = r * N + (pb << 7) + (wave << 4) + col;
  int qidx = perm[p];
  int qb = buckets[r * N + qidx];
  int q_start = offsets[r * NB + qb];
  int q_end = q_start + counts[r * NB + qb];

  if (tid == 0) sse[0] = q_start;
  if (tid == 511) sse[1] = q_end;
  for (int e = tid; e < KT * VST; e += 512) ((int*)v_lds)[e] = 0;

  s16x8 qa[2];
#pragma unroll
  for (int s2 = 0; s2 < 2; ++s2)
    qa[s2] = *(const s16x8*)(qkb + (size_t)qidx * HD + s2 * 32 + quad * 8);

  int wbs = __shfl(q_start, 0);
  int wbe = __shfl(q_end, 15);
  __syncthreads();
  int bs = sse[0], be = sse[1];

  float lsum = 0.f;
  f32x4 o0 = {0,0,0,0}, o1 = {0,0,0,0}, o2 = {0,0,0,0}, o3 = {0,0,0,0};

  int jsk = tid >> 2, csk = tid & 3;
  bool stager = tid < 256;
  int kgran = jsk * KST + ((csk ^ (jsk & 3)) << 4);
  int vgran = jsk * VST + (csk << 4);

  {
    int nj = min(KT, be - bs);
    if (stager && jsk < nj) {
      int g = perm[bs + jsk];
      const s16x8* kp = (const s16x8*)(qkb + (size_t)g * HD + (csk << 4));
      const s16x8* vp = (const s16x8*)(vb + (size_t)g * HD + (csk << 4));
      s16x8 a0 = kp[0], a1 = kp[1], b0 = vp[0], b1 = vp[1];
      s16x8* kd = (s16x8*)&k_lds[0][kgran];
      kd[0] = a0; kd[1] = a1;
      s16x8* vd = (s16x8*)&v_lds[0][vgran];
      vd[0] = b0; vd[1] = b1;
    }
  }
  __syncthreads();

  int ntiles = (be - bs + KT - 1) >> 6;
  for (int t = 0; t < ntiles; ++t) {
    int jt = bs + (t << 6);
    int cur = t & 1, nxt = cur ^ 1;
    s16x8 a0, a1, b0, b1;
    bool pf_ok = false;
    int jn = jt + KT;
    if (jn < be && stager) {
      int njn = min(KT, be - jn);
      if (jsk < njn) {
        pf_ok = true;
        int g = perm[jn + jsk];
        const s16x8* kp = (const s16x8*)(qkb + (size_t)g * HD + (csk << 4));
        const s16x8* vp = (const s16x8*)(vb + (size_t)g * HD + (csk << 4));
        a0 = kp[0]; a1 = kp[1]; b0 = vp[0]; b1 = vp[1];
      }
    }
    if (jt < wbe && jt + KT > wbs) {
      int c_lo = (wbs > jt) ? ((wbs - jt) >> 4) : 0;
      int c_hi = min(4, (wbe - jt + 15) >> 4);
      for (int c16 = c_lo; c16 < c_hi; ++c16) {
        f32x4 sacc = {0,0,0,0};
        int key = (c16 << 4) + col;
        const short* kb = &k_lds[cur][key * KST];
#pragma unroll
        for (int s2 = 0; s2 < 2; ++s2) {
          int cidx = ((s2 << 1) + (quad >> 1)) ^ (key & 3);
          s16x8 kf = *(const s16x8*)&kb[(cidx << 4) + ((quad & 1) << 3)];
          sacc = __builtin_amdgcn_mfma_f32_16x16x32_bf16(kf, qa[s2], sacc, 0, 0, 0);
        }
        int kbase = jt + (c16 << 4) + (quad << 2);
        float pw[4];
#pragma unroll
        for (int u = 0; u < 4; ++u) {
          int pos = kbase + u;
          bool ok = (pos >= q_start) && (pos < q_end);
          pw[u] = ok ? __expf(sacc[u] * SCALE) : 0.f;
        }
        lsum += (pw[0] + pw[1]) + (pw[2] + pw[3]);
        s16x4 pfr;
        pfr[0] = f2bf(pw[0]); pfr[1] = f2bf(pw[1]);
        pfr[2] = f2bf(pw[2]); pfr[3] = f2bf(pw[3]);
        const short* vbp = &v_lds[cur][((c16 << 4) + (quad << 2)) * VST + col];
#pragma unroll
        for (int c = 0; c < 4; ++c) {
          s16x4 vfr;
#pragma unroll
          for (int j = 0; j < 4; ++j)
            vfr[j] = vbp[j * VST + (c << 4)];
          if (c == 0) o0 = MFMA_PV(pfr, vfr, o0);
          else if (c == 1) o1 = MFMA_PV(pfr, vfr, o1);
          else if (c == 2) o2 = MFMA_PV(pfr, vfr, o2);
          else o3 = MFMA_PV(pfr, vfr, o3);
        }
      }
    }
    if (pf_ok) {
      s16x8* kd = (s16x8*)&k_lds[nxt][kgran];
      kd[0] = a0; kd[1] = a1;
      s16x8* vd = (s16x8*)&v_lds[nxt][vgran];
      vd[0] = b0; vd[1] = b1;
    }
    __syncthreads();
  }

  lsum += __shfl_xor(lsum, 16);
  lsum += __shfl_xor(lsum, 32);
  float inv = 1.f / lsum;
#pragma unroll
  for (int u = 0; u < 4; ++u) {
    int slot = (quad << 2) + u;
    float inv_u = __shfl(inv, slot);
    int qidx_u = __shfl(qidx, slot);
    float* dst = accumR + ((size_t)r * N + qidx_u) * HD + col;
    dst[0]  = o0[u] * inv_u;
    dst[16] = o1[u] * inv_u;
    dst[32] = o2[u] * inv_u;
    dst[48] = o3[u] * inv_u;
  }
}

// ---------------- K5: MFMA output projection (verbatim r9)
__global__ __launch_bounds__(256) void outproj_kernel(
    const float* __restrict__ accumR, const short* __restrict__ wto,
    const float* __restrict__ bo, float* __restrict__ out) {
  int mt = blockIdx.x & 31;   // s-tile of 32
  int nt = blockIdx.x >> 5;   // d-tile of 64
  __shared__ short a_lds[2][32 * PST];
  __shared__ short b_lds[2][64 * PST];
  int tid = threadIdx.x;
  int wave = tid >> 6, lane = tid & 63;
  int col = lane & 15, quad = lane >> 4;
  int mi2 = wave & 1, nh2 = wave >> 1;

  f32x4 acc[2];
  acc[0] = (f32x4){0.f,0.f,0.f,0.f};
  acc[1] = (f32x4){0.f,0.f,0.f,0.f};

  bool isA = tid < 128;
  int sr = tid >> 2, c4 = tid & 3;
  int agran = sr * PST + ((c4 ^ (sr & 3)) << 4);
  int dl = (tid - 128) >> 1, gp = tid & 1;

  {  // stage chunk 0
    if (isA) {
      size_t abase = ((size_t)0 * S + mt * 32 + sr) * HD + c4 * 16;
      f32x4 s0 = {0,0,0,0}, s1 = {0,0,0,0}, s2v = {0,0,0,0}, s3v = {0,0,0,0};
#pragma unroll
      for (int r = 0; r < NH; ++r) {
        const f32x4* ap = (const f32x4*)(accumR + (size_t)r * N * HD + abase);
        s0 += ap[0]; s1 += ap[1]; s2v += ap[2]; s3v += ap[3];
      }
      s16x8 ha, hb;
#pragma unroll
      for (int i = 0; i < 4; ++i) {
        ha[i] = f2bf(s0[i] * 0.125f); ha[4 + i] = f2bf(s1[i] * 0.125f);
        hb[i] = f2bf(s2v[i] * 0.125f); hb[4 + i] = f2bf(s3v[i] * 0.125f);
      }
      s16x8* ad = (s16x8*)&a_lds[0][agran];
      ad[0] = ha; ad[1] = hb;
    } else {
      const s16x8* wp = (const s16x8*)(wto + (size_t)(nt * 64 + dl) * DM + gp * 32);
      int g0 = gp * 2;
      s16x8* d0 = (s16x8*)&b_lds[0][dl * PST + ((g0 ^ (dl & 3)) << 4)];
      d0[0] = wp[0]; d0[1] = wp[1];
      s16x8* d1 = (s16x8*)&b_lds[0][dl * PST + (((g0 + 1) ^ (dl & 3)) << 4)];
      d1[0] = wp[2]; d1[1] = wp[3];
    }
  }
  __syncthreads();

  for (int kc = 0; kc < 8; ++kc) {
    int cur = kc & 1, nxt = cur ^ 1;
    bool has = kc + 1 < 8;
    f32x4 s0 = {0,0,0,0}, s1 = {0,0,0,0}, s2v = {0,0,0,0}, s3v = {0,0,0,0};
    s16x8 pb0, pb1, pb2, pb3;
    if (has) {
      if (isA) {
        size_t abase = ((size_t)(kc + 1) * S + mt * 32 + sr) * HD + c4 * 16;
#pragma unroll
        for (int r = 0; r < NH; ++r) {
          const f32x4* ap = (const f32x4*)(accumR + (size_t)r * N * HD + abase);
          s0 += ap[0]; s1 += ap[1]; s2v += ap[2]; s3v += ap[3];
        }
      } else {
        const s16x8* wp = (const s16x8*)(wto + (size_t)(nt * 64 + dl) * DM +
                                         (kc + 1) * 64 + gp * 32);
        pb0 = wp[0]; pb1 = wp[1]; pb2 = wp[2]; pb3 = wp[3];
      }
    }
#pragma unroll
    for (int s2 = 0; s2 < 2; ++s2) {
      int arow = mi2 * 16 + col;
      int acidx = ((s2 << 1) + (quad >> 1)) ^ (arow & 3);
      s16x8 af = *(const s16x8*)&a_lds[cur][arow * PST + (acidx << 4) + ((quad & 1) << 3)];
      s16x8 bfv[2];
#pragma unroll
      for (int ni = 0; ni < 2; ++ni) {
        int brow = nh2 * 32 + ni * 16 + col;
        int bcidx = ((s2 << 1) + (quad >> 1)) ^ (brow & 3);
        bfv[ni] = *(const s16x8*)&b_lds[cur][brow * PST + (bcidx << 4) + ((quad & 1) << 3)];
      }
#pragma unroll
      for (int ni = 0; ni < 2; ++ni)
        acc[ni] = __builtin_amdgcn_mfma_f32_16x16x32_bf16(af, bfv[ni], acc[ni], 0, 0, 0);
    }
    if (has) {
      if (isA) {
        s16x8 ha, hb;
#pragma unroll
        for (int i = 0; i < 4; ++i) {
          ha[i] = f2bf(s0[i] * 0.125f); ha[4 + i] = f2bf(s1[i] * 0.125f);
          hb[i] = f2bf(s2v[i] * 0.125f); hb[4 + i] = f2bf(s3v[i] * 0.125f);
        }
        s16x8* ad = (s16x8*)&a_lds[nxt][agran];
        ad[0] = ha; ad[1] = hb;
      } else {
        int g0 = gp * 2;
        s16x8* d0 = (s16x8*)&b_lds[nxt][dl * PST + ((g0 ^ (dl & 3)) << 4)];
        d0[0] = pb0; d0[1] = pb1;
        s16x8* d1 = (s16x8*)&b_lds[nxt][dl * PST + (((g0 + 1) ^ (dl & 3)) << 4)];
        d1[0] = pb2; d1[1] = pb3;
      }
    }
    __syncthreads();
  }
#pragma unroll
  for (int ni = 0; ni < 2; ++ni) {
    int nl = nh2 * 32 + ni * 16 + col;
    int dgl = nt * 64 + nl;
    float bb = bo[dgl];
#pragma unroll
    for (int u = 0; u < 4; ++u) {
      int s = mt * 32 + mi2 * 16 + quad * 4 + u;
      out[(size_t)s * DM + dgl] = acc[ni][u] + bb;
    }
  }
}

extern "C" void kernel_launch(void* const* d_in, const int* in_sizes, int n_in,
                              void* d_out, int out_size, void* d_ws, size_t ws_size,
                              hipStream_t stream) {
  const float* x    = (const float*)d_in[0];
  const float* w_qk = (const float*)d_in[1];
  const float* b_qk = (const float*)d_in[2];
  const float* w_v  = (const float*)d_in[3];
  const float* b_v  = (const float*)d_in[4];
  const float* w_o  = (const float*)d_in[5];
  const float* b_o  = (const float*)d_in[6];
  const float* rot  = (const float*)d_in[7];
  float* out = (float*)d_out;

  char* ws = (char*)d_ws;
  const size_t MB = 1024u * 1024u;
  short* qkb    = (short*)(ws);                       // 1 MB bf16
  short* vb     = (short*)(ws + 1 * MB);              // 1 MB bf16
  float* accumR = (float*)(ws + 2 * MB);              // 16 MB
  float* qkpart = accumR;                             // 12 MB, aliases accumR
                                                      // (dead before attn writes)
  short* wtqk   = (short*)(ws + 18 * MB);             // 1.5 MB (3 levels)
  short* wtv    = (short*)(ws + 18 * MB + 1536u * 1024);  // 0.5 MB
  short* wto    = (short*)(ws + 20 * MB);             // 0.5 MB
  int* buckets  = (int*)(ws + 20 * MB + 512u * 1024); // 256 KB
  int* perm     = (int*)(ws + 20 * MB + 768u * 1024); // 256 KB
  int* counts   = (int*)(ws + 21 * MB);               // 128 ints
  int* cursor   = counts + 128;                       // 128 ints
  int* offsets  = cursor + 128;                       // 128 ints

  wprep_kernel<<<192, 256, 0, stream>>>(w_qk, w_v, w_o, wtqk, wtv, wto, counts);
  projmm_kernel<<<896, 256, 0, stream>>>(x, wtqk, wtv, b_qk, b_v, qkpart, vb);
  bucket_kernel<<<(NH * N) / 256, 256, 0, stream>>>(qkpart, rot, buckets,
                                                    counts, qkb);
  scatter_kernel<<<(NH * N) / 256, 256, 0, stream>>>(buckets, counts, cursor,
                                                     offsets, perm);
  attn_kernel<<<NH * 64, 512, 0, stream>>>(qkb, vb, perm, buckets,
                                           offsets, counts, accumR);
  outproj_kernel<<<256, 256, 0, stream>>>(accumR, wto, b_o, out);
}

// Round 11
// 243.363 us; speedup vs baseline: 1.7560x; 1.0905x over previous
//
#include <hip/hip_runtime.h>
#include <math.h>

#define S 1024
#define DM 512
#define H 8
#define HD 64
#define NH 8          // n_hashes
#define NB 16         // n_buckets
#define N 8192        // B*H*S
#define SCALE 0.125f  // 1/sqrt(64)

typedef __attribute__((ext_vector_type(4))) float f32x4;
typedef __attribute__((ext_vector_type(8))) short s16x8;
typedef __attribute__((ext_vector_type(4))) short s16x4;

__device__ __forceinline__ short f2bf(float f) {  // RTNE float->bf16
  union { float f; unsigned u; } a; a.f = f;
  unsigned r = a.u + 0x7fffu + ((a.u >> 16) & 1u);
  return (short)(r >> 16);
}
__device__ __forceinline__ float bf2f(short h) {
  union { unsigned u; float f; } a; a.u = ((unsigned)(unsigned short)h) << 16;
  return a.f;
}
__device__ __forceinline__ int f2bf2(float lo, float hi) {
  return (int)(unsigned short)f2bf(lo) | (((int)f2bf(hi)) << 16);
}
// level-l component of the 3-way bf16 split x = x0 + x1 + x2 (+eps)
__device__ __forceinline__ short lev_bf(float v, int lev) {
  short h0 = f2bf(v);
  if (lev == 0) return h0;
  float r1 = v - bf2f(h0);
  short h1 = f2bf(r1);
  if (lev == 1) return h1;
  return f2bf(r1 - bf2f(h1));
}

#if __has_builtin(__builtin_amdgcn_mfma_f32_16x16x16_bf16)
#define MFMA_PV(a, b, c) __builtin_amdgcn_mfma_f32_16x16x16_bf16(a, b, c, 0, 0, 0)
#else
#define MFMA_PV(a, b, c) __builtin_amdgcn_mfma_f32_16x16x16bf16_1k(a, b, c, 0, 0, 0)
#endif

// ---------------- K0: weight prep — Wt[lev][d][k] bf16 (transposed, split)
__global__ __launch_bounds__(256) void wprep_kernel(
    const float* __restrict__ wqk, const float* __restrict__ wv,
    const float* __restrict__ wo,
    short* __restrict__ wtqk, short* __restrict__ wtv, short* __restrict__ wto,
    int* __restrict__ cz) {
  int tid = threadIdx.x;
  if (blockIdx.x == 0) cz[tid] = 0;   // counts[128] + cursor[128]
  int mat = blockIdx.x >> 6;          // 0 qk, 1 v, 2 o
  int tile = blockIdx.x & 63;
  int kt = tile >> 3, dt = tile & 7;
  const float* w = (mat == 0) ? wqk : ((mat == 1) ? wv : wo);

  __shared__ float wlds[64 * 68];
  int kr = tid >> 2, c4 = tid & 3;
  const float4* src = (const float4*)(w + (size_t)(kt * 64 + kr) * DM + dt * 64 + c4 * 16);
#pragma unroll
  for (int i = 0; i < 4; ++i) {
    float4 v = src[i];
    float* d = &wlds[kr * 68 + c4 * 16 + i * 4];
    d[0] = v.x; d[1] = v.y; d[2] = v.z; d[3] = v.w;
  }
  __syncthreads();
  int dr = tid >> 2, kc = tid & 3;
  s16x8 h0a, h0b, h1a, h1b, h2a, h2b;
#pragma unroll
  for (int i = 0; i < 8; ++i) {
    float v = wlds[(kc * 16 + i) * 68 + dr];
    short a = f2bf(v); float r1 = v - bf2f(a);
    short b = f2bf(r1); short c = f2bf(r1 - bf2f(b));
    h0a[i] = a; h1a[i] = b; h2a[i] = c;
  }
#pragma unroll
  for (int i = 0; i < 8; ++i) {
    float v = wlds[(kc * 16 + 8 + i) * 68 + dr];
    short a = f2bf(v); float r1 = v - bf2f(a);
    short b = f2bf(r1); short c = f2bf(r1 - bf2f(b));
    h0b[i] = a; h1b[i] = b; h2b[i] = c;
  }
  size_t dst = (size_t)(dt * 64 + dr) * DM + kt * 64 + kc * 16;
  if (mat == 0) {
    s16x8* p0 = (s16x8*)(wtqk + dst);
    s16x8* p1 = (s16x8*)(wtqk + (size_t)DM * DM + dst);
    s16x8* p2 = (s16x8*)(wtqk + (size_t)2 * DM * DM + dst);
    p0[0] = h0a; p0[1] = h0b; p1[0] = h1a; p1[1] = h1b; p2[0] = h2a; p2[1] = h2b;
  } else if (mat == 1) {
    s16x8* p = (s16x8*)(wtv + dst); p[0] = h0a; p[1] = h0b;
  } else {
    s16x8* p = (s16x8*)(wto + dst); p[0] = h0a; p[1] = h0b;
  }
}

// ---------------- K1: MFMA projection GEMM, split-K balanced (verbatim r10)
#define PST 72
__global__ __launch_bounds__(256) void projmm_kernel(
    const float* __restrict__ x, const short* __restrict__ wtqk,
    const short* __restrict__ wtv,
    const float* __restrict__ bqk, const float* __restrict__ bv,
    float* __restrict__ qkpart, short* __restrict__ vb) {
  int mt = blockIdx.x & 15;
  int rest = blockIdx.x >> 4;   // 0..55
  int sp = rest >> 3;           // 0..5 qk split, 6 = v
  int head = rest & 7;
  bool isv = (sp == 6);
  int xl = isv ? 0 : ((0x210100 >> (sp << 2)) & 0xF);  // {0,0,1,0,1,2}
  int wl = isv ? 0 : ((0x012010 >> (sp << 2)) & 0xF);  // {0,1,0,2,1,0}
  const short* wt = isv ? wtv : (wtqk + (size_t)wl * DM * DM);

  __shared__ short a_lds[2][64 * PST];
  __shared__ short b_lds[2][64 * PST];

  int tid = threadIdx.x;
  int wave = tid >> 6, lane = tid & 63;
  int col = lane & 15, quad = lane >> 4;
  int mh = wave & 1, nh2 = wave >> 1;

  f32x4 acc[2][2];
#pragma unroll
  for (int i = 0; i < 2; ++i)
#pragma unroll
    for (int j = 0; j < 2; ++j) acc[i][j] = (f32x4){0.f, 0.f, 0.f, 0.f};

  int sr = tid >> 2, c4 = tid & 3;
  int gran = sr * PST + ((c4 ^ (sr & 3)) << 4);

  {  // stage chunk 0 into buffer 0
    const float4* xp = (const float4*)(x + (size_t)(mt * 64 + sr) * DM + c4 * 16);
    float4 f0 = xp[0], f1 = xp[1], f2 = xp[2], f3 = xp[3];
    float vv[16] = {f0.x,f0.y,f0.z,f0.w, f1.x,f1.y,f1.z,f1.w,
                    f2.x,f2.y,f2.z,f2.w, f3.x,f3.y,f3.z,f3.w};
    s16x8 ha, hb;
#pragma unroll
    for (int i = 0; i < 8; ++i) { ha[i] = lev_bf(vv[i], xl); hb[i] = lev_bf(vv[8 + i], xl); }
    s16x8* ad = (s16x8*)&a_lds[0][gran];
    ad[0] = ha; ad[1] = hb;
    const s16x8* wp = (const s16x8*)(wt + (size_t)(head * 64 + sr) * DM + c4 * 16);
    s16x8* bd = (s16x8*)&b_lds[0][gran];
    bd[0] = wp[0]; bd[1] = wp[1];
  }
  __syncthreads();

  for (int ci = 0; ci < 8; ++ci) {
    int cur = ci & 1, nxt = cur ^ 1;
    float4 pf0, pf1, pf2, pf3; s16x8 pw0, pw1;
    bool has = (ci + 1) < 8;
    if (has) {
      int kc = ci + 1;
      const float4* xp = (const float4*)(x + (size_t)(mt * 64 + sr) * DM + kc * 64 + c4 * 16);
      pf0 = xp[0]; pf1 = xp[1]; pf2 = xp[2]; pf3 = xp[3];
      const s16x8* wp = (const s16x8*)(wt + (size_t)(head * 64 + sr) * DM + kc * 64 + c4 * 16);
      pw0 = wp[0]; pw1 = wp[1];
    }
#pragma unroll
    for (int s2 = 0; s2 < 2; ++s2) {
      s16x8 af[2], bfv[2];
#pragma unroll
      for (int mi = 0; mi < 2; ++mi) {
        int row = mh * 32 + mi * 16 + col;
        int cidx = ((s2 << 1) + (quad >> 1)) ^ (row & 3);
        af[mi] = *(const s16x8*)&a_lds[cur][row * PST + (cidx << 4) + ((quad & 1) << 3)];
      }
#pragma unroll
      for (int ni = 0; ni < 2; ++ni) {
        int row = nh2 * 32 + ni * 16 + col;
        int cidx = ((s2 << 1) + (quad >> 1)) ^ (row & 3);
        bfv[ni] = *(const s16x8*)&b_lds[cur][row * PST + (cidx << 4) + ((quad & 1) << 3)];
      }
#pragma unroll
      for (int mi = 0; mi < 2; ++mi)
#pragma unroll
        for (int ni = 0; ni < 2; ++ni)
          acc[mi][ni] = __builtin_amdgcn_mfma_f32_16x16x32_bf16(af[mi], bfv[ni],
                                                               acc[mi][ni], 0, 0, 0);
    }
    if (has) {
      float vv[16] = {pf0.x,pf0.y,pf0.z,pf0.w, pf1.x,pf1.y,pf1.z,pf1.w,
                      pf2.x,pf2.y,pf2.z,pf2.w, pf3.x,pf3.y,pf3.z,pf3.w};
      s16x8 ha, hb;
#pragma unroll
      for (int i = 0; i < 8; ++i) { ha[i] = lev_bf(vv[i], xl); hb[i] = lev_bf(vv[8 + i], xl); }
      s16x8* ad = (s16x8*)&a_lds[nxt][gran];
      ad[0] = ha; ad[1] = hb;
      s16x8* bd = (s16x8*)&b_lds[nxt][gran];
      bd[0] = pw0; bd[1] = pw1;
    }
    __syncthreads();
  }
  if (isv) {
#pragma unroll
    for (int ni = 0; ni < 2; ++ni) {
      int nl = nh2 * 32 + ni * 16 + col;
      float bb = bv[head * 64 + nl];
#pragma unroll
      for (int mi = 0; mi < 2; ++mi)
#pragma unroll
        for (int u = 0; u < 4; ++u) {
          int s = mt * 64 + mh * 32 + mi * 16 + quad * 4 + u;
          vb[((size_t)head * S + s) * HD + nl] = f2bf(acc[mi][ni][u] + bb);
        }
    }
  } else {
    float* dst = qkpart + (size_t)sp * N * HD;
#pragma unroll
    for (int ni = 0; ni < 2; ++ni) {
      int nl = nh2 * 32 + ni * 16 + col;
      float bb = (sp == 0) ? bqk[head * 64 + nl] : 0.f;
#pragma unroll
      for (int mi = 0; mi < 2; ++mi)
#pragma unroll
        for (int u = 0; u < 4; ++u) {
          int s = mt * 64 + mh * 32 + mi * 16 + quad * 4 + u;
          dst[((size_t)head * S + s) * HD + nl] = acc[mi][ni][u] + bb;
        }
    }
  }
}

// ---------------- K2a: collapse the 6 fp32 slabs once -> qkf fp32 + qkb bf16
__global__ __launch_bounds__(256) void sumslab_kernel(
    const float* __restrict__ qkpart, float* __restrict__ qkf,
    short* __restrict__ qkb) {
  int idx = blockIdx.x * 256 + threadIdx.x;  // 0 .. N*HD/4 - 1
  f32x4 s = ((const f32x4*)qkpart)[idx];
#pragma unroll
  for (int sl = 1; sl < 6; ++sl)
    s += ((const f32x4*)(qkpart + (size_t)sl * N * HD))[idx];
  ((f32x4*)qkf)[idx] = s;
  int2 pk = make_int2(f2bf2(s[0], s[1]), f2bf2(s[2], s[3]));
  *(int2*)(qkb + (size_t)idx * 4) = pk;
}

// ---------------- K2b: LSH buckets: rotation block staged in LDS (one (r,h)
// per block; 256 | 1024 so the mapping is exact), broadcast LDS reads.
__global__ __launch_bounds__(256) void bucket_kernel(
    const float* __restrict__ qkf, const float* __restrict__ rot,
    int* __restrict__ buckets, int* __restrict__ counts) {
  __shared__ float Rl[HD * 8];   // 512 floats = 2 KB
  int tid = threadIdx.x;
  int g = blockIdx.x * 256 + tid;
  int n = g & (N - 1);
  int r = g >> 13;
  int h = n >> 10;
  int lane = tid & 63;
  const float* R = rot + (size_t)((r * H + h) * HD) * 8;
  if (tid < 128) ((f32x4*)Rl)[tid] = ((const f32x4*)R)[tid];
  __syncthreads();

  const f32x4* q4 = (const f32x4*)(qkf + (size_t)n * HD);
  float v[8];
#pragma unroll
  for (int c = 0; c < 8; ++c) v[c] = 0.f;
  for (int d4 = 0; d4 < 16; ++d4) {
    f32x4 q = q4[d4];
#pragma unroll
    for (int j = 0; j < 4; ++j) {
      const f32x4* Rr = (const f32x4*)&Rl[(d4 * 4 + j) * 8];
      f32x4 r0 = Rr[0], r1 = Rr[1];
      float qj = q[j];
#pragma unroll
      for (int c = 0; c < 4; ++c) v[c] = fmaf(qj, r0[c], v[c]);
#pragma unroll
      for (int c = 0; c < 4; ++c) v[4 + c] = fmaf(qj, r1[c], v[4 + c]);
    }
  }
  float best = v[0];
  int bi = 0;
#pragma unroll
  for (int c = 1; c < 16; ++c) {
    float val = (c < 8) ? v[c] : -v[c - 8];
    if (val > best) { best = val; bi = c; }
  }
  buckets[r * N + n] = bi;
  for (int bk = 0; bk < NB; ++bk) {
    unsigned long long mask = __ballot(bi == bk);
    if (mask && lane == (__ffsll((long long)mask) - 1))
      atomicAdd(&counts[r * NB + bk], __popcll(mask));
  }
}

// ---------------- K3: scatter with fused scan (verbatim)
__global__ __launch_bounds__(256) void scatter_kernel(
    const int* __restrict__ buckets, const int* __restrict__ counts,
    int* __restrict__ cursor, int* __restrict__ offsets,
    int* __restrict__ perm) {
  __shared__ int cnt_s[128];
  __shared__ int off_s[128];
  int tid = threadIdx.x;
  if (tid < 128) cnt_s[tid] = counts[tid];
  __syncthreads();
  if (tid < 128) {
    int r = tid >> 4, b = tid & 15;
    int off = r * N;
    for (int i = 0; i < b; ++i) off += cnt_s[(r << 4) + i];
    off_s[tid] = off;
    if (blockIdx.x == 0) offsets[tid] = off;
  }
  __syncthreads();
  int g = blockIdx.x * 256 + tid;
  int n = g & (N - 1);
  int r = g >> 13;
  int lane = tid & 63;
  int b = buckets[r * N + n];
  for (int bk = 0; bk < NB; ++bk) {
    unsigned long long mask = __ballot(b == bk);
    if (!mask) continue;
    int leader = __ffsll((long long)mask) - 1;
    int base = 0;
    if (lane == leader) base = atomicAdd(&cursor[(r << 4) + bk], __popcll(mask));
    base = __shfl(base, leader);
    if (b == bk) {
      int rank = __popcll(mask & ((1ull << lane) - 1ull));
      perm[off_s[(r << 4) + bk] + base + rank] = n;
    }
  }
}

// ---------------- K4: MFMA attention (verbatim r8)
#define KT 64
#define KST 72
#define VST 72
__global__ __launch_bounds__(512) void attn_kernel(
    const short* __restrict__ qkb, const short* __restrict__ vb,
    const int* __restrict__ perm, const int* __restrict__ buckets,
    const int* __restrict__ offsets, const int* __restrict__ counts,
    float* __restrict__ accumR) {
  int r = blockIdx.x >> 6;
  int pb = blockIdx.x & 63;
  int tid = threadIdx.x;
  int wave = tid >> 6, lane = tid & 63;
  int col = lane & 15, quad = lane >> 4;

  __shared__ short k_lds[2][KT * KST];
  __shared__ short v_lds[2][KT * VST];
  __shared__ int sse[2];

  int p = r * N + (pb << 7) + (wave << 4) + col;
  int qidx = perm[p];
  int qb = buckets[r * N + qidx];
  int q_start = offsets[r * NB + qb];
  int q_end = q_start + counts[r * NB + qb];

  if (tid == 0) sse[0] = q_start;
  if (tid == 511) sse[1] = q_end;
  for (int e = tid; e < KT * VST; e += 512) ((int*)v_lds)[e] = 0;

  s16x8 qa[2];
#pragma unroll
  for (int s2 = 0; s2 < 2; ++s2)
    qa[s2] = *(const s16x8*)(qkb + (size_t)qidx * HD + s2 * 32 + quad * 8);

  int wbs = __shfl(q_start, 0);
  int wbe = __shfl(q_end, 15);
  __syncthreads();
  int bs = sse[0], be = sse[1];

  float lsum = 0.f;
  f32x4 o0 = {0,0,0,0}, o1 = {0,0,0,0}, o2 = {0,0,0,0}, o3 = {0,0,0,0};

  int jsk = tid >> 2, csk = tid & 3;
  bool stager = tid < 256;
  int kgran = jsk * KST + ((csk ^ (jsk & 3)) << 4);
  int vgran = jsk * VST + (csk << 4);

  {
    int nj = min(KT, be - bs);
    if (stager && jsk < nj) {
      int g = perm[bs + jsk];
      const s16x8* kp = (const s16x8*)(qkb + (size_t)g * HD + (csk << 4));
      const s16x8* vp = (const s16x8*)(vb + (size_t)g * HD + (csk << 4));
      s16x8 a0 = kp[0], a1 = kp[1], b0 = vp[0], b1 = vp[1];
      s16x8* kd = (s16x8*)&k_lds[0][kgran];
      kd[0] = a0; kd[1] = a1;
      s16x8* vd = (s16x8*)&v_lds[0][vgran];
      vd[0] = b0; vd[1] = b1;
    }
  }
  __syncthreads();

  int ntiles = (be - bs + KT - 1) >> 6;
  for (int t = 0; t < ntiles; ++t) {
    int jt = bs + (t << 6);
    int cur = t & 1, nxt = cur ^ 1;
    s16x8 a0, a1, b0, b1;
    bool pf_ok = false;
    int jn = jt + KT;
    if (jn < be && stager) {
      int njn = min(KT, be - jn);
      if (jsk < njn) {
        pf_ok = true;
        int g = perm[jn + jsk];
        const s16x8* kp = (const s16x8*)(qkb + (size_t)g * HD + (csk << 4));
        const s16x8* vp = (const s16x8*)(vb + (size_t)g * HD + (csk << 4));
        a0 = kp[0]; a1 = kp[1]; b0 = vp[0]; b1 = vp[1];
      }
    }
    if (jt < wbe && jt + KT > wbs) {
      int c_lo = (wbs > jt) ? ((wbs - jt) >> 4) : 0;
      int c_hi = min(4, (wbe - jt + 15) >> 4);
      for (int c16 = c_lo; c16 < c_hi; ++c16) {
        f32x4 sacc = {0,0,0,0};
        int key = (c16 << 4) + col;
        const short* kb = &k_lds[cur][key * KST];
#pragma unroll
        for (int s2 = 0; s2 < 2; ++s2) {
          int cidx = ((s2 << 1) + (quad >> 1)) ^ (key & 3);
          s16x8 kf = *(const s16x8*)&kb[(cidx << 4) + ((quad & 1) << 3)];
          sacc = __builtin_amdgcn_mfma_f32_16x16x32_bf16(kf, qa[s2], sacc, 0, 0, 0);
        }
        int kbase = jt + (c16 << 4) + (quad << 2);
        float pw[4];
#pragma unroll
        for (int u = 0; u < 4; ++u) {
          int pos = kbase + u;
          bool ok = (pos >= q_start) && (pos < q_end);
          pw[u] = ok ? __expf(sacc[u] * SCALE) : 0.f;
        }
        lsum += (pw[0] + pw[1]) + (pw[2] + pw[3]);
        s16x4 pfr;
        pfr[0] = f2bf(pw[0]); pfr[1] = f2bf(pw[1]);
        pfr[2] = f2bf(pw[2]); pfr[3] = f2bf(pw[3]);
        const short* vbp = &v_lds[cur][((c16 << 4) + (quad << 2)) * VST + col];
#pragma unroll
        for (int c = 0; c < 4; ++c) {
          s16x4 vfr;
#pragma unroll
          for (int j = 0; j < 4; ++j)
            vfr[j] = vbp[j * VST + (c << 4)];
          if (c == 0) o0 = MFMA_PV(pfr, vfr, o0);
          else if (c == 1) o1 = MFMA_PV(pfr, vfr, o1);
          else if (c == 2) o2 = MFMA_PV(pfr, vfr, o2);
          else o3 = MFMA_PV(pfr, vfr, o3);
        }
      }
    }
    if (pf_ok) {
      s16x8* kd = (s16x8*)&k_lds[nxt][kgran];
      kd[0] = a0; kd[1] = a1;
      s16x8* vd = (s16x8*)&v_lds[nxt][vgran];
      vd[0] = b0; vd[1] = b1;
    }
    __syncthreads();
  }

  lsum += __shfl_xor(lsum, 16);
  lsum += __shfl_xor(lsum, 32);
  float inv = 1.f / lsum;
#pragma unroll
  for (int u = 0; u < 4; ++u) {
    int slot = (quad << 2) + u;
    float inv_u = __shfl(inv, slot);
    int qidx_u = __shfl(qidx, slot);
    float* dst = accumR + ((size_t)r * N + qidx_u) * HD + col;
    dst[0]  = o0[u] * inv_u;
    dst[16] = o1[u] * inv_u;
    dst[32] = o2[u] * inv_u;
    dst[48] = o3[u] * inv_u;
  }
}

// ---------------- K5: MFMA output projection (verbatim)
__global__ __launch_bounds__(256) void outproj_kernel(
    const float* __restrict__ accumR, const short* __restrict__ wto,
    const float* __restrict__ bo, float* __restrict__ out) {
  int mt = blockIdx.x & 31;   // s-tile of 32
  int nt = blockIdx.x >> 5;   // d-tile of 64
  __shared__ short a_lds[2][32 * PST];
  __shared__ short b_lds[2][64 * PST];
  int tid = threadIdx.x;
  int wave = tid >> 6, lane = tid & 63;
  int col = lane & 15, quad = lane >> 4;
  int mi2 = wave & 1, nh2 = wave >> 1;

  f32x4 acc[2];
  acc[0] = (f32x4){0.f,0.f,0.f,0.f};
  acc[1] = (f32x4){0.f,0.f,0.f,0.f};

  bool isA = tid < 128;
  int sr = tid >> 2, c4 = tid & 3;
  int agran = sr * PST + ((c4 ^ (sr & 3)) << 4);
  int dl = (tid - 128) >> 1, gp = tid & 1;

  {  // stage chunk 0
    if (isA) {
      size_t abase = ((size_t)0 * S + mt * 32 + sr) * HD + c4 * 16;
      f32x4 s0 = {0,0,0,0}, s1 = {0,0,0,0}, s2v = {0,0,0,0}, s3v = {0,0,0,0};
#pragma unroll
      for (int r = 0; r < NH; ++r) {
        const f32x4* ap = (const f32x4*)(accumR + (size_t)r * N * HD + abase);
        s0 += ap[0]; s1 += ap[1]; s2v += ap[2]; s3v += ap[3];
      }
      s16x8 ha, hb;
#pragma unroll
      for (int i = 0; i < 4; ++i) {
        ha[i] = f2bf(s0[i] * 0.125f); ha[4 + i] = f2bf(s1[i] * 0.125f);
        hb[i] = f2bf(s2v[i] * 0.125f); hb[4 + i] = f2bf(s3v[i] * 0.125f);
      }
      s16x8* ad = (s16x8*)&a_lds[0][agran];
      ad[0] = ha; ad[1] = hb;
    } else {
      const s16x8* wp = (const s16x8*)(wto + (size_t)(nt * 64 + dl) * DM + gp * 32);
      int g0 = gp * 2;
      s16x8* d0 = (s16x8*)&b_lds[0][dl * PST + ((g0 ^ (dl & 3)) << 4)];
      d0[0] = wp[0]; d0[1] = wp[1];
      s16x8* d1 = (s16x8*)&b_lds[0][dl * PST + (((g0 + 1) ^ (dl & 3)) << 4)];
      d1[0] = wp[2]; d1[1] = wp[3];
    }
  }
  __syncthreads();

  for (int kc = 0; kc < 8; ++kc) {
    int cur = kc & 1, nxt = cur ^ 1;
    bool has = kc + 1 < 8;
    f32x4 s0 = {0,0,0,0}, s1 = {0,0,0,0}, s2v = {0,0,0,0}, s3v = {0,0,0,0};
    s16x8 pb0, pb1, pb2, pb3;
    if (has) {
      if (isA) {
        size_t abase = ((size_t)(kc + 1) * S + mt * 32 + sr) * HD + c4 * 16;
#pragma unroll
        for (int r = 0; r < NH; ++r) {
          const f32x4* ap = (const f32x4*)(accumR + (size_t)r * N * HD + abase);
          s0 += ap[0]; s1 += ap[1]; s2v += ap[2]; s3v += ap[3];
        }
      } else {
        const s16x8* wp = (const s16x8*)(wto + (size_t)(nt * 64 + dl) * DM +
                                         (kc + 1) * 64 + gp * 32);
        pb0 = wp[0]; pb1 = wp[1]; pb2 = wp[2]; pb3 = wp[3];
      }
    }
#pragma unroll
    for (int s2 = 0; s2 < 2; ++s2) {
      int arow = mi2 * 16 + col;
      int acidx = ((s2 << 1) + (quad >> 1)) ^ (arow & 3);
      s16x8 af = *(const s16x8*)&a_lds[cur][arow * PST + (acidx << 4) + ((quad & 1) << 3)];
      s16x8 bfv[2];
#pragma unroll
      for (int ni = 0; ni < 2; ++ni) {
        int brow = nh2 * 32 + ni * 16 + col;
        int bcidx = ((s2 << 1) + (quad >> 1)) ^ (brow & 3);
        bfv[ni] = *(const s16x8*)&b_lds[cur][brow * PST + (bcidx << 4) + ((quad & 1) << 3)];
      }
#pragma unroll
      for (int ni = 0; ni < 2; ++ni)
        acc[ni] = __builtin_amdgcn_mfma_f32_16x16x32_bf16(af, bfv[ni], acc[ni], 0, 0, 0);
    }
    if (has) {
      if (isA) {
        s16x8 ha, hb;
#pragma unroll
        for (int i = 0; i < 4; ++i) {
          ha[i] = f2bf(s0[i] * 0.125f); ha[4 + i] = f2bf(s1[i] * 0.125f);
          hb[i] = f2bf(s2v[i] * 0.125f); hb[4 + i] = f2bf(s3v[i] * 0.125f);
        }
        s16x8* ad = (s16x8*)&a_lds[nxt][agran];
        ad[0] = ha; ad[1] = hb;
      } else {
        int g0 = gp * 2;
        s16x8* d0 = (s16x8*)&b_lds[nxt][dl * PST + ((g0 ^ (dl & 3)) << 4)];
        d0[0] = pb0; d0[1] = pb1;
        s16x8* d1 = (s16x8*)&b_lds[nxt][dl * PST + (((g0 + 1) ^ (dl & 3)) << 4)];
        d1[0] = pb2; d1[1] = pb3;
      }
    }
    __syncthreads();
  }
#pragma unroll
  for (int ni = 0; ni < 2; ++ni) {
    int nl = nh2 * 32 + ni * 16 + col;
    int dgl = nt * 64 + nl;
    float bb = bo[dgl];
#pragma unroll
    for (int u = 0; u < 4; ++u) {
      int s = mt * 32 + mi2 * 16 + quad * 4 + u;
      out[(size_t)s * DM + dgl] = acc[ni][u] + bb;
    }
  }
}

extern "C" void kernel_launch(void* const* d_in, const int* in_sizes, int n_in,
                              void* d_out, int out_size, void* d_ws, size_t ws_size,
                              hipStream_t stream) {
  const float* x    = (const float*)d_in[0];
  const float* w_qk = (const float*)d_in[1];
  const float* b_qk = (const float*)d_in[2];
  const float* w_v  = (const float*)d_in[3];
  const float* b_v  = (const float*)d_in[4];
  const float* w_o  = (const float*)d_in[5];
  const float* b_o  = (const float*)d_in[6];
  const float* rot  = (const float*)d_in[7];
  float* out = (float*)d_out;

  char* ws = (char*)d_ws;
  const size_t MB = 1024u * 1024u;
  short* qkb    = (short*)(ws);                       // 1 MB bf16
  short* vb     = (short*)(ws + 1 * MB);              // 1 MB bf16
  float* accumR = (float*)(ws + 2 * MB);              // 16 MB
  float* qkpart = accumR;                             // 12 MB, aliases accumR
                                                      // (dead before attn writes)
  float* qkf    = (float*)(ws + 18 * MB);             // 2 MB fp32 (hash input)
  short* wtqk   = (short*)(ws + 20 * MB);             // 1.5 MB (3 levels)
  short* wtv    = (short*)(ws + 20 * MB + 1536u * 1024);  // 0.5 MB
  short* wto    = (short*)(ws + 22 * MB);             // 0.5 MB
  int* buckets  = (int*)(ws + 22 * MB + 512u * 1024); // 256 KB
  int* perm     = (int*)(ws + 22 * MB + 768u * 1024); // 256 KB
  int* counts   = (int*)(ws + 23 * MB);               // 128 ints
  int* cursor   = counts + 128;                       // 128 ints
  int* offsets  = cursor + 128;                       // 128 ints

  wprep_kernel<<<192, 256, 0, stream>>>(w_qk, w_v, w_o, wtqk, wtv, wto, counts);
  projmm_kernel<<<896, 256, 0, stream>>>(x, wtqk, wtv, b_qk, b_v, qkpart, vb);
  sumslab_kernel<<<512, 256, 0, stream>>>(qkpart, qkf, qkb);
  bucket_kernel<<<(NH * N) / 256, 256, 0, stream>>>(qkf, rot, buckets, counts);
  scatter_kernel<<<(NH * N) / 256, 256, 0, stream>>>(buckets, counts, cursor,
                                                     offsets, perm);
  attn_kernel<<<NH * 64, 512, 0, stream>>>(qkb, vb, perm, buckets,
                                           offsets, counts, accumR);
  outproj_kernel<<<256, 256, 0, stream>>>(accumR, wto, b_o, out);
}

// Round 12
// 231.878 us; speedup vs baseline: 1.8430x; 1.0495x over previous
//
#include <hip/hip_runtime.h>
#include <math.h>

#define S 1024
#define DM 512
#define H 8
#define HD 64
#define NH 8          // n_hashes
#define NB 16         // n_buckets
#define N 8192        // B*H*S
#define SCALE 0.125f  // 1/sqrt(64)
#define EXP2C 0.18033688f  // SCALE * log2(e)

typedef __attribute__((ext_vector_type(4))) float f32x4;
typedef __attribute__((ext_vector_type(8))) short s16x8;
typedef __attribute__((ext_vector_type(4))) short s16x4;

__device__ __forceinline__ short f2bf(float f) {  // RTNE float->bf16
  union { float f; unsigned u; } a; a.f = f;
  unsigned r = a.u + 0x7fffu + ((a.u >> 16) & 1u);
  return (short)(r >> 16);
}
__device__ __forceinline__ float bf2f(short h) {
  union { unsigned u; float f; } a; a.u = ((unsigned)(unsigned short)h) << 16;
  return a.f;
}
__device__ __forceinline__ int f2bf2(float lo, float hi) {
  return (int)(unsigned short)f2bf(lo) | (((int)f2bf(hi)) << 16);
}
// level-l component of the 3-way bf16 split x = x0 + x1 + x2 (+eps)
__device__ __forceinline__ short lev_bf(float v, int lev) {
  short h0 = f2bf(v);
  if (lev == 0) return h0;
  float r1 = v - bf2f(h0);
  short h1 = f2bf(r1);
  if (lev == 1) return h1;
  return f2bf(r1 - bf2f(h1));
}

#if __has_builtin(__builtin_amdgcn_mfma_f32_16x16x16_bf16)
#define MFMA_PV(a, b, c) __builtin_amdgcn_mfma_f32_16x16x16_bf16(a, b, c, 0, 0, 0)
#else
#define MFMA_PV(a, b, c) __builtin_amdgcn_mfma_f32_16x16x16bf16_1k(a, b, c, 0, 0, 0)
#endif

// ---------------- K0: weight prep — Wt[lev][d][k] bf16 (transposed, split)
__global__ __launch_bounds__(256) void wprep_kernel(
    const float* __restrict__ wqk, const float* __restrict__ wv,
    const float* __restrict__ wo,
    short* __restrict__ wtqk, short* __restrict__ wtv, short* __restrict__ wto,
    int* __restrict__ cz) {
  int tid = threadIdx.x;
  if (blockIdx.x == 0) cz[tid] = 0;   // counts[128] + cursor[128]
  int mat = blockIdx.x >> 6;          // 0 qk, 1 v, 2 o
  int tile = blockIdx.x & 63;
  int kt = tile >> 3, dt = tile & 7;
  const float* w = (mat == 0) ? wqk : ((mat == 1) ? wv : wo);

  __shared__ float wlds[64 * 68];
  int kr = tid >> 2, c4 = tid & 3;
  const float4* src = (const float4*)(w + (size_t)(kt * 64 + kr) * DM + dt * 64 + c4 * 16);
#pragma unroll
  for (int i = 0; i < 4; ++i) {
    float4 v = src[i];
    float* d = &wlds[kr * 68 + c4 * 16 + i * 4];
    d[0] = v.x; d[1] = v.y; d[2] = v.z; d[3] = v.w;
  }
  __syncthreads();
  int dr = tid >> 2, kc = tid & 3;
  s16x8 h0a, h0b, h1a, h1b, h2a, h2b;
#pragma unroll
  for (int i = 0; i < 8; ++i) {
    float v = wlds[(kc * 16 + i) * 68 + dr];
    short a = f2bf(v); float r1 = v - bf2f(a);
    short b = f2bf(r1); short c = f2bf(r1 - bf2f(b));
    h0a[i] = a; h1a[i] = b; h2a[i] = c;
  }
#pragma unroll
  for (int i = 0; i < 8; ++i) {
    float v = wlds[(kc * 16 + 8 + i) * 68 + dr];
    short a = f2bf(v); float r1 = v - bf2f(a);
    short b = f2bf(r1); short c = f2bf(r1 - bf2f(b));
    h0b[i] = a; h1b[i] = b; h2b[i] = c;
  }
  size_t dst = (size_t)(dt * 64 + dr) * DM + kt * 64 + kc * 16;
  if (mat == 0) {
    s16x8* p0 = (s16x8*)(wtqk + dst);
    s16x8* p1 = (s16x8*)(wtqk + (size_t)DM * DM + dst);
    s16x8* p2 = (s16x8*)(wtqk + (size_t)2 * DM * DM + dst);
    p0[0] = h0a; p0[1] = h0b; p1[0] = h1a; p1[1] = h1b; p2[0] = h2a; p2[1] = h2b;
  } else if (mat == 1) {
    s16x8* p = (s16x8*)(wtv + dst); p[0] = h0a; p[1] = h0b;
  } else {
    s16x8* p = (s16x8*)(wto + dst); p[0] = h0a; p[1] = h0b;
  }
}

// ---------------- K1: MFMA projection GEMM, split-K balanced (verbatim r10)
#define PST 72
__global__ __launch_bounds__(256) void projmm_kernel(
    const float* __restrict__ x, const short* __restrict__ wtqk,
    const short* __restrict__ wtv,
    const float* __restrict__ bqk, const float* __restrict__ bv,
    float* __restrict__ qkpart, short* __restrict__ vb) {
  int mt = blockIdx.x & 15;
  int rest = blockIdx.x >> 4;   // 0..55
  int sp = rest >> 3;           // 0..5 qk split, 6 = v
  int head = rest & 7;
  bool isv = (sp == 6);
  int xl = isv ? 0 : ((0x210100 >> (sp << 2)) & 0xF);  // {0,0,1,0,1,2}
  int wl = isv ? 0 : ((0x012010 >> (sp << 2)) & 0xF);  // {0,1,0,2,1,0}
  const short* wt = isv ? wtv : (wtqk + (size_t)wl * DM * DM);

  __shared__ short a_lds[2][64 * PST];
  __shared__ short b_lds[2][64 * PST];

  int tid = threadIdx.x;
  int wave = tid >> 6, lane = tid & 63;
  int col = lane & 15, quad = lane >> 4;
  int mh = wave & 1, nh2 = wave >> 1;

  f32x4 acc[2][2];
#pragma unroll
  for (int i = 0; i < 2; ++i)
#pragma unroll
    for (int j = 0; j < 2; ++j) acc[i][j] = (f32x4){0.f, 0.f, 0.f, 0.f};

  int sr = tid >> 2, c4 = tid & 3;
  int gran = sr * PST + ((c4 ^ (sr & 3)) << 4);

  {  // stage chunk 0 into buffer 0
    const float4* xp = (const float4*)(x + (size_t)(mt * 64 + sr) * DM + c4 * 16);
    float4 f0 = xp[0], f1 = xp[1], f2 = xp[2], f3 = xp[3];
    float vv[16] = {f0.x,f0.y,f0.z,f0.w, f1.x,f1.y,f1.z,f1.w,
                    f2.x,f2.y,f2.z,f2.w, f3.x,f3.y,f3.z,f3.w};
    s16x8 ha, hb;
#pragma unroll
    for (int i = 0; i < 8; ++i) { ha[i] = lev_bf(vv[i], xl); hb[i] = lev_bf(vv[8 + i], xl); }
    s16x8* ad = (s16x8*)&a_lds[0][gran];
    ad[0] = ha; ad[1] = hb;
    const s16x8* wp = (const s16x8*)(wt + (size_t)(head * 64 + sr) * DM + c4 * 16);
    s16x8* bd = (s16x8*)&b_lds[0][gran];
    bd[0] = wp[0]; bd[1] = wp[1];
  }
  __syncthreads();

  for (int ci = 0; ci < 8; ++ci) {
    int cur = ci & 1, nxt = cur ^ 1;
    float4 pf0, pf1, pf2, pf3; s16x8 pw0, pw1;
    bool has = (ci + 1) < 8;
    if (has) {
      int kc = ci + 1;
      const float4* xp = (const float4*)(x + (size_t)(mt * 64 + sr) * DM + kc * 64 + c4 * 16);
      pf0 = xp[0]; pf1 = xp[1]; pf2 = xp[2]; pf3 = xp[3];
      const s16x8* wp = (const s16x8*)(wt + (size_t)(head * 64 + sr) * DM + kc * 64 + c4 * 16);
      pw0 = wp[0]; pw1 = wp[1];
    }
#pragma unroll
    for (int s2 = 0; s2 < 2; ++s2) {
      s16x8 af[2], bfv[2];
#pragma unroll
      for (int mi = 0; mi < 2; ++mi) {
        int row = mh * 32 + mi * 16 + col;
        int cidx = ((s2 << 1) + (quad >> 1)) ^ (row & 3);
        af[mi] = *(const s16x8*)&a_lds[cur][row * PST + (cidx << 4) + ((quad & 1) << 3)];
      }
#pragma unroll
      for (int ni = 0; ni < 2; ++ni) {
        int row = nh2 * 32 + ni * 16 + col;
        int cidx = ((s2 << 1) + (quad >> 1)) ^ (row & 3);
        bfv[ni] = *(const s16x8*)&b_lds[cur][row * PST + (cidx << 4) + ((quad & 1) << 3)];
      }
#pragma unroll
      for (int mi = 0; mi < 2; ++mi)
#pragma unroll
        for (int ni = 0; ni < 2; ++ni)
          acc[mi][ni] = __builtin_amdgcn_mfma_f32_16x16x32_bf16(af[mi], bfv[ni],
                                                               acc[mi][ni], 0, 0, 0);
    }
    if (has) {
      float vv[16] = {pf0.x,pf0.y,pf0.z,pf0.w, pf1.x,pf1.y,pf1.z,pf1.w,
                      pf2.x,pf2.y,pf2.z,pf2.w, pf3.x,pf3.y,pf3.z,pf3.w};
      s16x8 ha, hb;
#pragma unroll
      for (int i = 0; i < 8; ++i) { ha[i] = lev_bf(vv[i], xl); hb[i] = lev_bf(vv[8 + i], xl); }
      s16x8* ad = (s16x8*)&a_lds[nxt][gran];
      ad[0] = ha; ad[1] = hb;
      s16x8* bd = (s16x8*)&b_lds[nxt][gran];
      bd[0] = pw0; bd[1] = pw1;
    }
    __syncthreads();
  }
  if (isv) {
#pragma unroll
    for (int ni = 0; ni < 2; ++ni) {
      int nl = nh2 * 32 + ni * 16 + col;
      float bb = bv[head * 64 + nl];
#pragma unroll
      for (int mi = 0; mi < 2; ++mi)
#pragma unroll
        for (int u = 0; u < 4; ++u) {
          int s = mt * 64 + mh * 32 + mi * 16 + quad * 4 + u;
          vb[((size_t)head * S + s) * HD + nl] = f2bf(acc[mi][ni][u] + bb);
        }
    }
  } else {
    float* dst = qkpart + (size_t)sp * N * HD;
#pragma unroll
    for (int ni = 0; ni < 2; ++ni) {
      int nl = nh2 * 32 + ni * 16 + col;
      float bb = (sp == 0) ? bqk[head * 64 + nl] : 0.f;
#pragma unroll
      for (int mi = 0; mi < 2; ++mi)
#pragma unroll
        for (int u = 0; u < 4; ++u) {
          int s = mt * 64 + mh * 32 + mi * 16 + quad * 4 + u;
          dst[((size_t)head * S + s) * HD + nl] = acc[mi][ni][u] + bb;
        }
    }
  }
}

// ---------------- K2a: collapse the 6 fp32 slabs once -> qkf fp32 + qkb bf16
__global__ __launch_bounds__(256) void sumslab_kernel(
    const float* __restrict__ qkpart, float* __restrict__ qkf,
    short* __restrict__ qkb) {
  int idx = blockIdx.x * 256 + threadIdx.x;  // 0 .. N*HD/4 - 1
  f32x4 s = ((const f32x4*)qkpart)[idx];
#pragma unroll
  for (int sl = 1; sl < 6; ++sl)
    s += ((const f32x4*)(qkpart + (size_t)sl * N * HD))[idx];
  ((f32x4*)qkf)[idx] = s;
  int2 pk = make_int2(f2bf2(s[0], s[1]), f2bf2(s[2], s[3]));
  *(int2*)(qkb + (size_t)idx * 4) = pk;
}

// ---------------- K2b: LSH buckets: rotation block staged in LDS
__global__ __launch_bounds__(256) void bucket_kernel(
    const float* __restrict__ qkf, const float* __restrict__ rot,
    int* __restrict__ buckets, int* __restrict__ counts) {
  __shared__ float Rl[HD * 8];   // 512 floats = 2 KB
  int tid = threadIdx.x;
  int g = blockIdx.x * 256 + tid;
  int n = g & (N - 1);
  int r = g >> 13;
  int h = n >> 10;
  int lane = tid & 63;
  const float* R = rot + (size_t)((r * H + h) * HD) * 8;
  if (tid < 128) ((f32x4*)Rl)[tid] = ((const f32x4*)R)[tid];
  __syncthreads();

  const f32x4* q4 = (const f32x4*)(qkf + (size_t)n * HD);
  float v[8];
#pragma unroll
  for (int c = 0; c < 8; ++c) v[c] = 0.f;
  for (int d4 = 0; d4 < 16; ++d4) {
    f32x4 q = q4[d4];
#pragma unroll
    for (int j = 0; j < 4; ++j) {
      const f32x4* Rr = (const f32x4*)&Rl[(d4 * 4 + j) * 8];
      f32x4 r0 = Rr[0], r1 = Rr[1];
      float qj = q[j];
#pragma unroll
      for (int c = 0; c < 4; ++c) v[c] = fmaf(qj, r0[c], v[c]);
#pragma unroll
      for (int c = 0; c < 4; ++c) v[4 + c] = fmaf(qj, r1[c], v[4 + c]);
    }
  }
  float best = v[0];
  int bi = 0;
#pragma unroll
  for (int c = 1; c < 16; ++c) {
    float val = (c < 8) ? v[c] : -v[c - 8];
    if (val > best) { best = val; bi = c; }
  }
  buckets[r * N + n] = bi;
  for (int bk = 0; bk < NB; ++bk) {
    unsigned long long mask = __ballot(bi == bk);
    if (mask && lane == (__ffsll((long long)mask) - 1))
      atomicAdd(&counts[r * NB + bk], __popcll(mask));
  }
}

// ---------------- K3: scatter with fused scan (verbatim)
__global__ __launch_bounds__(256) void scatter_kernel(
    const int* __restrict__ buckets, const int* __restrict__ counts,
    int* __restrict__ cursor, int* __restrict__ offsets,
    int* __restrict__ perm) {
  __shared__ int cnt_s[128];
  __shared__ int off_s[128];
  int tid = threadIdx.x;
  if (tid < 128) cnt_s[tid] = counts[tid];
  __syncthreads();
  if (tid < 128) {
    int r = tid >> 4, b = tid & 15;
    int off = r * N;
    for (int i = 0; i < b; ++i) off += cnt_s[(r << 4) + i];
    off_s[tid] = off;
    if (blockIdx.x == 0) offsets[tid] = off;
  }
  __syncthreads();
  int g = blockIdx.x * 256 + tid;
  int n = g & (N - 1);
  int r = g >> 13;
  int lane = tid & 63;
  int b = buckets[r * N + n];
  for (int bk = 0; bk < NB; ++bk) {
    unsigned long long mask = __ballot(b == bk);
    if (!mask) continue;
    int leader = __ffsll((long long)mask) - 1;
    int base = 0;
    if (lane == leader) base = atomicAdd(&cursor[(r << 4) + bk], __popcll(mask));
    base = __shfl(base, leader);
    if (b == bk) {
      int rank = __popcll(mask & ((1ull << lane) - 1ull));
      perm[off_s[(r << 4) + bk] + base + rank] = n;
    }
  }
}

// ---------------- K4: MFMA attention. V in r5-verified TRANSPOSED layout
// (VST=66: store v_lds[d*VST + ((jh^(d&3))<<2|jl)], read grp=(c16*4+quad)^
// (col&3) -> two b32), halving LDS issue vs 16 scalar u16 reads. Fast-path
// mask via __all; exp2f with folded SCALE*log2e; bf16 normalized output.
#define KT 64
#define KST 72
#define VST 66
__global__ __launch_bounds__(512) void attn_kernel(
    const short* __restrict__ qkb, const short* __restrict__ vb,
    const int* __restrict__ perm, const int* __restrict__ buckets,
    const int* __restrict__ offsets, const int* __restrict__ counts,
    short* __restrict__ accumB) {
  int r = blockIdx.x >> 6;
  int pb = blockIdx.x & 63;
  int tid = threadIdx.x;
  int wave = tid >> 6, lane = tid & 63;
  int col = lane & 15, quad = lane >> 4;

  __shared__ short k_lds[2][KT * KST];
  __shared__ short v_lds[2][HD * VST];
  __shared__ int sse[2];

  int p = r * N + (pb << 7) + (wave << 4) + col;
  int qidx = perm[p];
  int qb = buckets[r * N + qidx];
  int q_start = offsets[r * NB + qb];
  int q_end = q_start + counts[r * NB + qb];

  if (tid == 0) sse[0] = q_start;
  if (tid == 511) sse[1] = q_end;
  for (int e = tid; e < HD * VST; e += 512) ((int*)v_lds)[e] = 0;

  s16x8 qa[2];
#pragma unroll
  for (int s2 = 0; s2 < 2; ++s2)
    qa[s2] = *(const s16x8*)(qkb + (size_t)qidx * HD + s2 * 32 + quad * 8);

  int wbs = __shfl(q_start, 0);
  int wbe = __shfl(q_end, 15);
  __syncthreads();
  int bs = sse[0], be = sse[1];

  float lsum = 0.f;
  f32x4 o0 = {0,0,0,0}, o1 = {0,0,0,0}, o2 = {0,0,0,0}, o3 = {0,0,0,0};

  int jsk = tid >> 2, csk = tid & 3;
  bool stager = tid < 256;
  int kgran = jsk * KST + ((csk ^ (jsk & 3)) << 4);
  int jh = jsk >> 2, jl = jsk & 3;

  {
    int nj = min(KT, be - bs);
    if (stager && jsk < nj) {
      int g = perm[bs + jsk];
      const s16x8* kp = (const s16x8*)(qkb + (size_t)g * HD + (csk << 4));
      const s16x8* vp = (const s16x8*)(vb + (size_t)g * HD + (csk << 4));
      s16x8 a0 = kp[0], a1 = kp[1], b0 = vp[0], b1 = vp[1];
      s16x8* kd = (s16x8*)&k_lds[0][kgran];
      kd[0] = a0; kd[1] = a1;
#pragma unroll
      for (int t = 0; t < 8; ++t) {
        int d = (csk << 4) + t;
        v_lds[0][d * VST + (((jh ^ (t & 3)) << 2) | jl)] = b0[t];
      }
#pragma unroll
      for (int t = 8; t < 16; ++t) {
        int d = (csk << 4) + t;
        v_lds[0][d * VST + (((jh ^ (t & 3)) << 2) | jl)] = b1[t - 8];
      }
    }
  }
  __syncthreads();

  int ntiles = (be - bs + KT - 1) >> 6;
  for (int t = 0; t < ntiles; ++t) {
    int jt = bs + (t << 6);
    int cur = t & 1, nxt = cur ^ 1;
    s16x8 a0, a1, b0, b1;
    bool pf_ok = false;
    int jn = jt + KT;
    if (jn < be && stager) {
      int njn = min(KT, be - jn);
      if (jsk < njn) {
        pf_ok = true;
        int g = perm[jn + jsk];
        const s16x8* kp = (const s16x8*)(qkb + (size_t)g * HD + (csk << 4));
        const s16x8* vp = (const s16x8*)(vb + (size_t)g * HD + (csk << 4));
        a0 = kp[0]; a1 = kp[1]; b0 = vp[0]; b1 = vp[1];
      }
    }
    if (jt < wbe && jt + KT > wbs) {
      int c_lo = (wbs > jt) ? ((wbs - jt) >> 4) : 0;
      int c_hi = min(4, (wbe - jt + 15) >> 4);
      for (int c16 = c_lo; c16 < c_hi; ++c16) {
        f32x4 sacc = {0,0,0,0};
        int key = (c16 << 4) + col;
        const short* kb = &k_lds[cur][key * KST];
#pragma unroll
        for (int s2 = 0; s2 < 2; ++s2) {
          int cidx = ((s2 << 1) + (quad >> 1)) ^ (key & 3);
          s16x8 kf = *(const s16x8*)&kb[(cidx << 4) + ((quad & 1) << 3)];
          sacc = __builtin_amdgcn_mfma_f32_16x16x32_bf16(kf, qa[s2], sacc, 0, 0, 0);
        }
        int kbase = jt + (c16 << 4) + (quad << 2);
        float pw[4];
        bool fin = (kbase >= q_start) && (kbase + 4 <= q_end);
        if (__all(fin)) {                 // common: whole chunk in-bucket
#pragma unroll
          for (int u = 0; u < 4; ++u) pw[u] = exp2f(sacc[u] * EXP2C);
        } else {
#pragma unroll
          for (int u = 0; u < 4; ++u) {
            int pos = kbase + u;
            bool ok = (pos >= q_start) && (pos < q_end);
            pw[u] = ok ? exp2f(sacc[u] * EXP2C) : 0.f;
          }
        }
        lsum += (pw[0] + pw[1]) + (pw[2] + pw[3]);
        s16x4 pfr;
        pfr[0] = f2bf(pw[0]); pfr[1] = f2bf(pw[1]);
        pfr[2] = f2bf(pw[2]); pfr[3] = f2bf(pw[3]);
        int grp = ((c16 << 2) + quad) ^ (col & 3);
#pragma unroll
        for (int c = 0; c < 4; ++c) {
          int dl = (c << 4) + col;
          int off = dl * VST + (grp << 2);
          int lo_ = *(const int*)&v_lds[cur][off];
          int hi_ = *(const int*)&v_lds[cur][off + 2];
          s16x4 vfr;
          vfr[0] = (short)(lo_ & 0xffff); vfr[1] = (short)(lo_ >> 16);
          vfr[2] = (short)(hi_ & 0xffff); vfr[3] = (short)(hi_ >> 16);
          if (c == 0) o0 = MFMA_PV(pfr, vfr, o0);
          else if (c == 1) o1 = MFMA_PV(pfr, vfr, o1);
          else if (c == 2) o2 = MFMA_PV(pfr, vfr, o2);
          else o3 = MFMA_PV(pfr, vfr, o3);
        }
      }
    }
    if (pf_ok) {
      s16x8* kd = (s16x8*)&k_lds[nxt][kgran];
      kd[0] = a0; kd[1] = a1;
#pragma unroll
      for (int u = 0; u < 8; ++u) {
        int d = (csk << 4) + u;
        v_lds[nxt][d * VST + (((jh ^ (u & 3)) << 2) | jl)] = b0[u];
      }
#pragma unroll
      for (int u = 8; u < 16; ++u) {
        int d = (csk << 4) + u;
        v_lds[nxt][d * VST + (((jh ^ (u & 3)) << 2) | jl)] = b1[u - 8];
      }
    }
    __syncthreads();
  }

  lsum += __shfl_xor(lsum, 16);
  lsum += __shfl_xor(lsum, 32);
  float inv = 1.f / lsum;
#pragma unroll
  for (int u = 0; u < 4; ++u) {
    int slot = (quad << 2) + u;
    float inv_u = __shfl(inv, slot);
    int qidx_u = __shfl(qidx, slot);
    short* dst = accumB + ((size_t)r * N + qidx_u) * HD + col;
    dst[0]  = f2bf(o0[u] * inv_u);
    dst[16] = f2bf(o1[u] * inv_u);
    dst[32] = f2bf(o2[u] * inv_u);
    dst[48] = f2bf(o3[u] * inv_u);
  }
}

// ---------------- K5: MFMA output projection; A from bf16 accumB (8 rounds
// summed in fp32 during staging — half the bytes of the fp32 version).
__global__ __launch_bounds__(256) void outproj_kernel(
    const short* __restrict__ accumB, const short* __restrict__ wto,
    const float* __restrict__ bo, float* __restrict__ out) {
  int mt = blockIdx.x & 31;   // s-tile of 32
  int nt = blockIdx.x >> 5;   // d-tile of 64
  __shared__ short a_lds[2][32 * PST];
  __shared__ short b_lds[2][64 * PST];
  int tid = threadIdx.x;
  int wave = tid >> 6, lane = tid & 63;
  int col = lane & 15, quad = lane >> 4;
  int mi2 = wave & 1, nh2 = wave >> 1;

  f32x4 acc[2];
  acc[0] = (f32x4){0.f,0.f,0.f,0.f};
  acc[1] = (f32x4){0.f,0.f,0.f,0.f};

  bool isA = tid < 128;
  int sr = tid >> 2, c4 = tid & 3;
  int agran = sr * PST + ((c4 ^ (sr & 3)) << 4);
  int dl = (tid - 128) >> 1, gp = tid & 1;

  {  // stage chunk 0
    if (isA) {
      size_t abase = ((size_t)0 * S + mt * 32 + sr) * HD + c4 * 16;
      float a16[16];
#pragma unroll
      for (int i = 0; i < 16; ++i) a16[i] = 0.f;
#pragma unroll
      for (int r = 0; r < NH; ++r) {
        const short* ap = accumB + (size_t)r * N * HD + abase;
        s16x8 h0 = *(const s16x8*)ap, h1 = *(const s16x8*)(ap + 8);
#pragma unroll
        for (int i = 0; i < 8; ++i) { a16[i] += bf2f(h0[i]); a16[8 + i] += bf2f(h1[i]); }
      }
      s16x8 ha, hb;
#pragma unroll
      for (int i = 0; i < 8; ++i) {
        ha[i] = f2bf(a16[i] * 0.125f); hb[i] = f2bf(a16[8 + i] * 0.125f);
      }
      s16x8* ad = (s16x8*)&a_lds[0][agran];
      ad[0] = ha; ad[1] = hb;
    } else {
      const s16x8* wp = (const s16x8*)(wto + (size_t)(nt * 64 + dl) * DM + gp * 32);
      int g0 = gp * 2;
      s16x8* d0 = (s16x8*)&b_lds[0][dl * PST + ((g0 ^ (dl & 3)) << 4)];
      d0[0] = wp[0]; d0[1] = wp[1];
      s16x8* d1 = (s16x8*)&b_lds[0][dl * PST + (((g0 + 1) ^ (dl & 3)) << 4)];
      d1[0] = wp[2]; d1[1] = wp[3];
    }
  }
  __syncthreads();

  for (int kc = 0; kc < 8; ++kc) {
    int cur = kc & 1, nxt = cur ^ 1;
    bool has = kc + 1 < 8;
    float a16[16];
    s16x8 pb0, pb1, pb2, pb3;
    if (has) {
      if (isA) {
        size_t abase = ((size_t)(kc + 1) * S + mt * 32 + sr) * HD + c4 * 16;
#pragma unroll
        for (int i = 0; i < 16; ++i) a16[i] = 0.f;
#pragma unroll
        for (int r = 0; r < NH; ++r) {
          const short* ap = accumB + (size_t)r * N * HD + abase;
          s16x8 h0 = *(const s16x8*)ap, h1 = *(const s16x8*)(ap + 8);
#pragma unroll
          for (int i = 0; i < 8; ++i) { a16[i] += bf2f(h0[i]); a16[8 + i] += bf2f(h1[i]); }
        }
      } else {
        const s16x8* wp = (const s16x8*)(wto + (size_t)(nt * 64 + dl) * DM +
                                         (kc + 1) * 64 + gp * 32);
        pb0 = wp[0]; pb1 = wp[1]; pb2 = wp[2]; pb3 = wp[3];
      }
    }
#pragma unroll
    for (int s2 = 0; s2 < 2; ++s2) {
      int arow = mi2 * 16 + col;
      int acidx = ((s2 << 1) + (quad >> 1)) ^ (arow & 3);
      s16x8 af = *(const s16x8*)&a_lds[cur][arow * PST + (acidx << 4) + ((quad & 1) << 3)];
      s16x8 bfv[2];
#pragma unroll
      for (int ni = 0; ni < 2; ++ni) {
        int brow = nh2 * 32 + ni * 16 + col;
        int bcidx = ((s2 << 1) + (quad >> 1)) ^ (brow & 3);
        bfv[ni] = *(const s16x8*)&b_lds[cur][brow * PST + (bcidx << 4) + ((quad & 1) << 3)];
      }
#pragma unroll
      for (int ni = 0; ni < 2; ++ni)
        acc[ni] = __builtin_amdgcn_mfma_f32_16x16x32_bf16(af, bfv[ni], acc[ni], 0, 0, 0);
    }
    if (has) {
      if (isA) {
        s16x8 ha, hb;
#pragma unroll
        for (int i = 0; i < 8; ++i) {
          ha[i] = f2bf(a16[i] * 0.125f); hb[i] = f2bf(a16[8 + i] * 0.125f);
        }
        s16x8* ad = (s16x8*)&a_lds[nxt][agran];
        ad[0] = ha; ad[1] = hb;
      } else {
        int g0 = gp * 2;
        s16x8* d0 = (s16x8*)&b_lds[nxt][dl * PST + ((g0 ^ (dl & 3)) << 4)];
        d0[0] = pb0; d0[1] = pb1;
        s16x8* d1 = (s16x8*)&b_lds[nxt][dl * PST + (((g0 + 1) ^ (dl & 3)) << 4)];
        d1[0] = pb2; d1[1] = pb3;
      }
    }
    __syncthreads();
  }
#pragma unroll
  for (int ni = 0; ni < 2; ++ni) {
    int nl = nh2 * 32 + ni * 16 + col;
    int dgl = nt * 64 + nl;
    float bb = bo[dgl];
#pragma unroll
    for (int u = 0; u < 4; ++u) {
      int s = mt * 32 + mi2 * 16 + quad * 4 + u;
      out[(size_t)s * DM + dgl] = acc[ni][u] + bb;
    }
  }
}

extern "C" void kernel_launch(void* const* d_in, const int* in_sizes, int n_in,
                              void* d_out, int out_size, void* d_ws, size_t ws_size,
                              hipStream_t stream) {
  const float* x    = (const float*)d_in[0];
  const float* w_qk = (const float*)d_in[1];
  const float* b_qk = (const float*)d_in[2];
  const float* w_v  = (const float*)d_in[3];
  const float* b_v  = (const float*)d_in[4];
  const float* w_o  = (const float*)d_in[5];
  const float* b_o  = (const float*)d_in[6];
  const float* rot  = (const float*)d_in[7];
  float* out = (float*)d_out;

  char* ws = (char*)d_ws;
  const size_t MB = 1024u * 1024u;
  short* qkb    = (short*)(ws);                       // 1 MB bf16
  short* vb     = (short*)(ws + 1 * MB);              // 1 MB bf16
  float* qkpart = (float*)(ws + 2 * MB);              // 12 MB (6 fp32 slabs)
  short* accumB = (short*)(ws + 2 * MB);              // 8.4 MB bf16, aliases
                                                      // qkpart (dead by attn)
  float* qkf    = (float*)(ws + 18 * MB);             // 2 MB fp32 (hash input)
  short* wtqk   = (short*)(ws + 20 * MB);             // 1.5 MB (3 levels)
  short* wtv    = (short*)(ws + 20 * MB + 1536u * 1024);  // 0.5 MB
  short* wto    = (short*)(ws + 22 * MB);             // 0.5 MB
  int* buckets  = (int*)(ws + 22 * MB + 512u * 1024); // 256 KB
  int* perm     = (int*)(ws + 22 * MB + 768u * 1024); // 256 KB
  int* counts   = (int*)(ws + 23 * MB);               // 128 ints
  int* cursor   = counts + 128;                       // 128 ints
  int* offsets  = cursor + 128;                       // 128 ints

  wprep_kernel<<<192, 256, 0, stream>>>(w_qk, w_v, w_o, wtqk, wtv, wto, counts);
  projmm_kernel<<<896, 256, 0, stream>>>(x, wtqk, wtv, b_qk, b_v, qkpart, vb);
  sumslab_kernel<<<512, 256, 0, stream>>>(qkpart, qkf, qkb);
  bucket_kernel<<<(NH * N) / 256, 256, 0, stream>>>(qkf, rot, buckets, counts);
  scatter_kernel<<<(NH * N) / 256, 256, 0, stream>>>(buckets, counts, cursor,
                                                     offsets, perm);
  attn_kernel<<<NH * 64, 512, 0, stream>>>(qkb, vb, perm, buckets,
                                           offsets, counts, accumB);
  outproj_kernel<<<256, 256, 0, stream>>>(accumB, wto, b_o, out);
}